// Round 4
// baseline (562.576 us; speedup 1.0000x reference)
//
#include <hip/hip_runtime.h>
#include <hip/hip_bf16.h>
#include <stdint.h>

// ---------- types ----------
typedef __attribute__((ext_vector_type(8))) short     short8;   // 8 bf16 (raw bits)
typedef __attribute__((ext_vector_type(8))) _Float16  f16x8;    // 8 fp16
typedef __attribute__((ext_vector_type(4))) float     f32x4;
typedef __attribute__((ext_vector_type(8))) unsigned short ushort8;
typedef __attribute__((ext_vector_type(4))) unsigned short ushort4_t;

// ---------- scalar conversion helpers ----------
__device__ inline unsigned short f2bf(float f) {
    unsigned u = __float_as_uint(f);
    u += 0x7fffu + ((u >> 16) & 1u);          // RNE
    return (unsigned short)(u >> 16);
}
__device__ inline float bf2f(unsigned short h) {
    return __uint_as_float(((unsigned)h) << 16);
}
__device__ inline unsigned short f2h(float f) {
    _Float16 h = (_Float16)f;
    unsigned short r;
    __builtin_memcpy(&r, &h, 2);
    return r;
}

// ---------- async global->LDS (width 16) ----------
__device__ inline void gload16(const void* g, void* lds) {
    unsigned loff = (unsigned)(uintptr_t)lds;
    loff = __builtin_amdgcn_readfirstlane(loff);
    auto l = (__attribute__((address_space(3))) unsigned int*)(uintptr_t)loff;
    auto p = (const __attribute__((address_space(1))) unsigned int*)(uintptr_t)g;
    __builtin_amdgcn_global_load_lds(p, l, 16, 0, 0);
}

// =====================================================================
// Batched elementwise f32 -> 2-byte: y=0 key->f16, y=1 query->f16, y=2 value->bf16
// =====================================================================
__global__ void cvt3_f32_2b(const float4* __restrict__ k, const float4* __restrict__ q,
                            const float4* __restrict__ v,
                            ushort4_t* __restrict__ k16, ushort4_t* __restrict__ q16,
                            ushort4_t* __restrict__ v16, int n4) {
    const int which = blockIdx.y;
    const float4* in  = which == 0 ? k   : which == 1 ? q   : v;
    ushort4_t*    out = which == 0 ? k16 : which == 1 ? q16 : v16;
    const bool tof16 = (which < 2);
    for (int i = blockIdx.x * blockDim.x + threadIdx.x; i < n4; i += gridDim.x * blockDim.x) {
        float4 vv = in[i];
        ushort4_t r;
        if (tof16) { r.x = f2h(vv.x);  r.y = f2h(vv.y);  r.z = f2h(vv.z);  r.w = f2h(vv.w); }
        else       { r.x = f2bf(vv.x); r.y = f2bf(vv.y); r.z = f2bf(vv.z); r.w = f2bf(vv.w); }
        out[i] = r;
    }
}

// =====================================================================
// Weight transpose + convert: W[dim][dim] f32 -> WT[n][k] 2-byte
// =====================================================================
template<int TOF16>
__global__ void transpose_cvt(const float* __restrict__ W, unsigned short* __restrict__ WT, int dim) {
    __shared__ float t[32][33];
    const int bx = blockIdx.x * 32, by = blockIdx.y * 32;   // bx: n, by: k
    const int tx = threadIdx.x, ty = threadIdx.y;
#pragma unroll
    for (int i = 0; i < 4; ++i)
        t[ty + 8 * i][tx] = W[(size_t)(by + ty + 8 * i) * dim + bx + tx];
    __syncthreads();
#pragma unroll
    for (int i = 0; i < 4; ++i) {
        float v = t[tx][ty + 8 * i];
        WT[(size_t)(bx + ty + 8 * i) * dim + by + tx] = TOF16 ? f2h(v) : f2bf(v);
    }
}

// =====================================================================
// v [128][1024][64] bf16 -> vT [128][64][1024] bf16
// =====================================================================
__global__ void transpose_v(const unsigned short* __restrict__ v, unsigned short* __restrict__ vT) {
    const int bh = blockIdx.z, d0 = blockIdx.x * 32, s0 = blockIdx.y * 32;
    __shared__ unsigned short t[32][33];
    const int tx = threadIdx.x, ty = threadIdx.y;
    const size_t base = (size_t)bh << 16;
#pragma unroll
    for (int i = 0; i < 4; ++i)
        t[ty + 8 * i][tx] = v[base + (size_t)(s0 + ty + 8 * i) * 64 + d0 + tx];
    __syncthreads();
#pragma unroll
    for (int i = 0; i < 4; ++i)
        vT[base + (size_t)(d0 + ty + 8 * i) * 1024 + s0 + tx] = t[tx][ty + 8 * i];
}

// =====================================================================
// GEMM (B^T form): C[M][N] = A[M][K] * W  where Bt[n][k] = W[k][n].
// m97 structure: 128x128 tile, BK=32, 4 waves (2x2), global_load_lds w16.
// EPI 0: store 2-byte (f16/bf16 per F16IN). EPI 1: f32 store of acc+bias+resid.
// =====================================================================
template<int F16IN, int EPI>
__global__ __launch_bounds__(256, 2) void gemm_bt(
    const unsigned short* __restrict__ A,
    const unsigned short* __restrict__ Bt,
    const float* __restrict__ bias,
    unsigned short* __restrict__ C2b,
    const float* __restrict__ resid,
    float* __restrict__ Cf,
    int M, int N, int K, int nbx)
{
    // XCD-chunked bijective swizzle (gridDim.x % 8 == 0)
    const int bid = blockIdx.x;
    const int cpx = gridDim.x >> 3;
    const int swz = (bid & 7) * cpx + (bid >> 3);
    const int bm = swz / nbx, bn = swz % nbx;
    const int m0 = bm * 128, n0 = bn * 128;

    const int tid = threadIdx.x;
    const int w = tid >> 6, l = tid & 63, g = l >> 4, c = l & 15;
    const int wr = w >> 1, wc = w & 1;

    __shared__ unsigned short As[4096];   // [128][32]
    __shared__ unsigned short Bs[4096];   // [128][32]

    f32x4 acc[4][4] = {};

    const int arow = tid >> 2, acol = (tid & 3) * 8;
    const unsigned short* Ap  = A  + (size_t)(m0 + arow) * K + acol;
    const unsigned short* Ap2 = A  + (size_t)(m0 + 64 + arow) * K + acol;
    const unsigned short* Bp  = Bt + (size_t)(n0 + arow) * K + acol;
    const unsigned short* Bp2 = Bt + (size_t)(n0 + 64 + arow) * K + acol;
    unsigned short* AsW  = &As[w * 512];
    unsigned short* AsW2 = &As[2048 + w * 512];
    unsigned short* BsW  = &Bs[w * 512];
    unsigned short* BsW2 = &Bs[2048 + w * 512];

    for (int k0 = 0; k0 < K; k0 += 32) {
        gload16(Ap + k0,  AsW);
        gload16(Ap2 + k0, AsW2);
        gload16(Bp + k0,  BsW);
        gload16(Bp2 + k0, BsW2);
        asm volatile("s_waitcnt vmcnt(0)" ::: "memory");
        __syncthreads();

        if constexpr (F16IN) {
            f16x8 a[4], b[4];
#pragma unroll
            for (int mt = 0; mt < 4; ++mt)
                a[mt] = *(const f16x8*)&As[(wr * 64 + mt * 16 + c) * 32 + g * 8];
#pragma unroll
            for (int nt = 0; nt < 4; ++nt)
                b[nt] = *(const f16x8*)&Bs[(wc * 64 + nt * 16 + c) * 32 + g * 8];
#pragma unroll
            for (int mt = 0; mt < 4; ++mt)
#pragma unroll
                for (int nt = 0; nt < 4; ++nt)
                    acc[mt][nt] = __builtin_amdgcn_mfma_f32_16x16x32_f16(a[mt], b[nt], acc[mt][nt], 0, 0, 0);
        } else {
            short8 a[4], b[4];
#pragma unroll
            for (int mt = 0; mt < 4; ++mt)
                a[mt] = *(const short8*)&As[(wr * 64 + mt * 16 + c) * 32 + g * 8];
#pragma unroll
            for (int nt = 0; nt < 4; ++nt)
                b[nt] = *(const short8*)&Bs[(wc * 64 + nt * 16 + c) * 32 + g * 8];
#pragma unroll
            for (int mt = 0; mt < 4; ++mt)
#pragma unroll
                for (int nt = 0; nt < 4; ++nt)
                    acc[mt][nt] = __builtin_amdgcn_mfma_f32_16x16x32_bf16(a[mt], b[nt], acc[mt][nt], 0, 0, 0);
        }
        __syncthreads();
    }

    // epilogue
#pragma unroll
    for (int nt = 0; nt < 4; ++nt) {
        const int col = n0 + wc * 64 + nt * 16 + c;
        const float bs = bias[col];
#pragma unroll
        for (int mt = 0; mt < 4; ++mt) {
            const int row0 = m0 + wr * 64 + mt * 16 + g * 4;
#pragma unroll
            for (int r = 0; r < 4; ++r) {
                const float x = acc[mt][nt][r] + bs;
                const size_t idx = (size_t)(row0 + r) * N + col;
                if constexpr (EPI == 0) {
                    C2b[idx] = F16IN ? f2h(x) : f2bf(x);
                } else {
                    Cf[idx] = x + resid[idx];
                }
            }
        }
    }
}

// =====================================================================
// Attention v3: swapped QK^T (mfma(K,Q)); unnormalized bf16 P -> XOR-swizzled
// LDS via packed ds_write_b64. Attention write goes LDS -> HBM one row per
// wave-instruction: ds_read_b128 half-row (row-uniform -> conflict-free),
// wave-uniform inv scale, 2 KB fully-contiguous stores per wave. No pt[]
// register array (VGPR ~55). PV from LDS P x pre-transposed vT.
// One block = (bh, 16 q-rows); 4 waves x 256 k-cols.
// =====================================================================
__global__ __launch_bounds__(256, 4) void attn_kernel(
    const unsigned short* __restrict__ qf,   // f16  [128*1024*64]
    const unsigned short* __restrict__ kf,   // f16  [128*1024*64]
    const unsigned short* __restrict__ vT,   // bf16 [128][64][1024]
    float* __restrict__ attn_out,            // f32  [128][1024][1024]
    unsigned short* __restrict__ ctx)        // bf16 [128*1024*64]
{
    const int rb = blockIdx.x;               // 0..63 (16-row blocks)
    const int bh = blockIdx.y;               // 0..127
    const int tid = threadIdx.x;
    const int w = tid >> 6, l = tid & 63, g = l >> 4, c = l & 15;
    const int n0 = w * 256;

    __shared__ unsigned short P[16 * 1024];  // 32 KB, XOR-swizzled by (row&7)<<4
    __shared__ float rs_lds[4][16];
    __shared__ float inv_lds[16];

    // Q fragment (B-operand): lane holds Q[row = rb*16 + c][d = g*8 .. +7] (+32)
    const unsigned short* qb = qf + ((size_t)bh << 16) + (size_t)(rb * 16 + c) * 64 + g * 8;
    const f16x8 q0 = *(const f16x8*)(qb);
    const f16x8 q1 = *(const f16x8*)(qb + 32);

    const unsigned short* kb = kf + ((size_t)bh << 16);
    const unsigned swzc = ((unsigned)(c & 7)) << 4;
    const unsigned prow = (unsigned)c * 2048;

    float rsum = 0.f;

    // QK^T: per t, A-operand = K rows (= attention cols) n0+t*16+c, d-chunk g*8.
    // Output: lane holds score[q = c][kcol = n0 + t*16 + g*4 + r].
#pragma unroll
    for (int t = 0; t < 16; ++t) {
        const unsigned short* kp = kb + (size_t)(n0 + t * 16 + c) * 64 + g * 8;
        const f16x8 a0 = *(const f16x8*)(kp);
        const f16x8 a1 = *(const f16x8*)(kp + 32);
        f32x4 s = {0.f, 0.f, 0.f, 0.f};
        s = __builtin_amdgcn_mfma_f32_16x16x32_f16(a0, q0, s, 0, 0, 0);
        s = __builtin_amdgcn_mfma_f32_16x16x32_f16(a1, q1, s, 0, 0, 0);

        const float p0 = __expf(s[0] * 0.5f);
        const float p1 = __expf(s[1] * 0.5f);
        const float p2 = __expf(s[2] * 0.5f);
        const float p3 = __expf(s[3] * 0.5f);
        rsum += (p0 + p1) + (p2 + p3);

        ushort4_t pk;
        pk.x = f2bf(p0); pk.y = f2bf(p1); pk.z = f2bf(p2); pk.w = f2bf(p3);
        // row = c, byte col = n0*2 + t*32 + g*8  (4 consecutive bf16 = 8B)
        *(ushort4_t*)((char*)P + ((prow + (unsigned)(n0 * 2 + t * 32 + g * 8)) ^ swzc)) = pk;
    }

    // row-sum for row c: reduce over the 4 lane-groups (lane-id bits 4,5)
    rsum += __shfl_xor(rsum, 16);
    rsum += __shfl_xor(rsum, 32);
    if (g == 0) rs_lds[w][c] = rsum;
    __syncthreads();                          // also covers P ds_writes
    if (tid < 16)
        inv_lds[tid] = 1.0f / (rs_lds[0][tid] + rs_lds[1][tid] + rs_lds[2][tid] + rs_lds[3][tid]);
    __syncthreads();

    // attention write: LDS -> HBM. Wave w handles rows w*4 .. w*4+3, one
    // half-row (512 cols) per iteration: 64 lanes x 8 cols = fully contiguous
    // 2 KB per wave-instruction. inv is wave-uniform (scalar broadcast).
    float* aob = attn_out + ((size_t)bh << 20) + (size_t)(rb * 16) * 1024;
#pragma unroll
    for (int it = 0; it < 8; ++it) {
        const int row  = w * 4 + (it >> 1);
        const int half = it & 1;
        const unsigned colb = (unsigned)(half * 1024 + l * 16);
        const ushort8 pv = *(const ushort8*)((char*)P +
            ((unsigned)row * 2048 + (colb ^ ((((unsigned)row & 7u)) << 4))));
        const float inv = inv_lds[row];
        f32x4 o0, o1;
        o0[0] = bf2f(pv[0]) * inv; o0[1] = bf2f(pv[1]) * inv;
        o0[2] = bf2f(pv[2]) * inv; o0[3] = bf2f(pv[3]) * inv;
        o1[0] = bf2f(pv[4]) * inv; o1[1] = bf2f(pv[5]) * inv;
        o1[2] = bf2f(pv[6]) * inv; o1[3] = bf2f(pv[7]) * inv;
        float* dst = aob + (size_t)row * 1024 + half * 512 + l * 8;
        *(f32x4*)(dst)     = o0;
        *(f32x4*)(dst + 4) = o1;
    }

    // PV: wave w owns output cols d = w*16 .. +15, K = 1024.
    // A-frag: P[row=c][k = ks*32 + g*8 ..+7] from swizzled LDS (b128).
    // B-frag: vT[w*16 + c][ks*32 + g*8 ..+7].
    f32x4 pacc = {0.f, 0.f, 0.f, 0.f};
    const unsigned short* vb = vT + ((size_t)bh << 16) + (size_t)(w * 16 + c) * 1024;
#pragma unroll 4
    for (int ks = 0; ks < 32; ++ks) {
        const short8 a = *(const short8*)((char*)P + ((prow + (unsigned)(ks * 64 + g * 16)) ^ swzc));
        const short8 b = *(const short8*)(vb + ks * 32 + g * 8);
        pacc = __builtin_amdgcn_mfma_f32_16x16x32_bf16(a, b, pacc, 0, 0, 0);
    }
    unsigned short* cb = ctx + ((size_t)bh << 16) + (size_t)(rb * 16) * 64 + w * 16 + c;
#pragma unroll
    for (int r = 0; r < 4; ++r) {
        const int row = g * 4 + r;
        cb[(size_t)row * 64] = f2bf(pacc[r] * inv_lds[row]);
    }
}

// =====================================================================
// BatchNorm over channels (deterministic two-level reduction)
// =====================================================================
__global__ void bn_stats(const float* __restrict__ x, float* __restrict__ psum, float* __restrict__ psq) {
    const int col = blockIdx.y * 256 + threadIdx.x;   // grid.y = 4
    const int r0 = blockIdx.x * 128;                  // grid.x = 64
    float s = 0.f, q = 0.f;
#pragma unroll 4
    for (int r = 0; r < 128; ++r) {
        const float v = x[(size_t)(r0 + r) * 1024 + col];
        s += v; q += v * v;
    }
    psum[blockIdx.x * 1024 + col] = s;
    psq [blockIdx.x * 1024 + col] = q;
}

__global__ void bn_final(const float* __restrict__ psum, const float* __restrict__ psq,
                         const float* __restrict__ gamma, const float* __restrict__ beta,
                         float* __restrict__ ab) {
    const int cidx = threadIdx.x;   // 1024 threads
    float s = 0.f, q = 0.f;
#pragma unroll 8
    for (int i = 0; i < 64; ++i) { s += psum[i * 1024 + cidx]; q += psq[i * 1024 + cidx]; }
    const float mean = s * (1.0f / 8192.0f);
    const float var  = q * (1.0f / 8192.0f) - mean * mean;
    const float a = gamma[cidx] * rsqrtf(var + 1e-5f);
    ab[cidx]        = a;
    ab[1024 + cidx] = beta[cidx] - mean * a;
}

__global__ void bn_apply(const float4* __restrict__ x4, const float* __restrict__ ab, float4* __restrict__ o4) {
    const int n4 = 2 * 1024 * 1024;
    for (int i = blockIdx.x * blockDim.x + threadIdx.x; i < n4; i += gridDim.x * blockDim.x) {
        const float4 v = x4[i];
        const int c0 = (i & 255) << 2;
        float4 r;
        r.x = v.x * ab[c0 + 0] + ab[1024 + c0 + 0];
        r.y = v.y * ab[c0 + 1] + ab[1024 + c0 + 1];
        r.z = v.z * ab[c0 + 2] + ab[1024 + c0 + 2];
        r.w = v.w * ab[c0 + 3] + ab[1024 + c0 + 3];
        o4[i] = r;
    }
}

// =====================================================================
// launch
// =====================================================================
extern "C" void kernel_launch(void* const* d_in, const int* in_sizes, int n_in,
                              void* d_out, int out_size, void* d_ws, size_t ws_size,
                              hipStream_t stream) {
    (void)in_sizes; (void)n_in; (void)out_size; (void)ws_size;

    const float* key   = (const float*)d_in[0];
    const float* value = (const float*)d_in[1];
    const float* query = (const float*)d_in[2];
    const float* Wk = (const float*)d_in[3];
    const float* bk = (const float*)d_in[4];
    const float* Wv = (const float*)d_in[5];
    const float* bv = (const float*)d_in[6];
    const float* Wq = (const float*)d_in[7];
    const float* bq = (const float*)d_in[8];
    const float* Wf = (const float*)d_in[9];
    const float* bff = (const float*)d_in[10];
    const float* gamma = (const float*)d_in[11];
    const float* beta  = (const float*)d_in[12];

    char* ws = (char*)d_ws;
    const size_t MB = 1u << 20;
    // layout (with safe overlap reuse):
    unsigned short* key16   = (unsigned short*)(ws + 0);        // dead after GEMM-k -> reused as ctx
    unsigned short* ctx     = (unsigned short*)(ws + 0);
    unsigned short* query16 = (unsigned short*)(ws + 16 * MB);  // dead after GEMM-q -+
    unsigned short* value16 = (unsigned short*)(ws + 32 * MB);  // dead after GEMM-v -+-> reused as xbuf
    float*          xbuf    = (float*)(ws + 16 * MB);           // 32 MB
    unsigned short* WkT = (unsigned short*)(ws + 48 * MB);
    unsigned short* WqT = (unsigned short*)(ws + 50 * MB);
    unsigned short* WvT = (unsigned short*)(ws + 52 * MB);
    unsigned short* WfT = (unsigned short*)(ws + 54 * MB);
    unsigned short* kbuf = (unsigned short*)(ws + 56 * MB);
    unsigned short* qbuf = (unsigned short*)(ws + 72 * MB);
    unsigned short* vbuf = (unsigned short*)(ws + 88 * MB);     // dead after transpose_v -> stats
    float* psum = (float*)(ws + 88 * MB);
    float* psq  = (float*)(ws + 88 * MB + 256 * 1024);
    float* ab   = (float*)(ws + 88 * MB + 512 * 1024);
    unsigned short* vTbuf = (unsigned short*)(ws + 104 * MB);
    // total: 120 MB

    float* out0 = (float*)d_out;            // [8M]  normalized output
    float* attn = out0 + 8388608;           // [128M] attention

    const int n4big = 2 * 1024 * 1024;      // 8M floats / 4

    // 1) input conversions (single batched launch)
    cvt3_f32_2b<<<dim3(1024, 3), 256, 0, stream>>>(
        (const float4*)key, (const float4*)query, (const float4*)value,
        (ushort4_t*)key16, (ushort4_t*)query16, (ushort4_t*)value16, n4big);

    // 2) weight transposes
    dim3 tb(32, 8), tg(32, 32);
    transpose_cvt<1><<<tg, tb, 0, stream>>>(Wk, WkT, 1024);
    transpose_cvt<1><<<tg, tb, 0, stream>>>(Wq, WqT, 1024);
    transpose_cvt<0><<<tg, tb, 0, stream>>>(Wv, WvT, 1024);
    transpose_cvt<0><<<tg, tb, 0, stream>>>(Wf, WfT, 1024);

    // 3) QKV projections (M=8192, N=1024, K=1024), f16 for q/k, bf16 for v
    gemm_bt<1, 0><<<512, 256, 0, stream>>>(key16,   WkT, bk, kbuf, nullptr, nullptr, 8192, 1024, 1024, 8);
    gemm_bt<1, 0><<<512, 256, 0, stream>>>(query16, WqT, bq, qbuf, nullptr, nullptr, 8192, 1024, 1024, 8);
    gemm_bt<0, 0><<<512, 256, 0, stream>>>(value16, WvT, bv, vbuf, nullptr, nullptr, 8192, 1024, 1024, 8);

    // 4) v -> vT per head-batch
    transpose_v<<<dim3(2, 32, 128), tb, 0, stream>>>(vbuf, vTbuf);

    // 5) attention (writes attention matrix + ctx)
    attn_kernel<<<dim3(64, 128), 256, 0, stream>>>(qbuf, kbuf, vTbuf, attn, ctx);

    // 6) output projection + residual -> xbuf (f32)
    gemm_bt<0, 1><<<512, 256, 0, stream>>>(ctx, WfT, bff, nullptr, query, xbuf, 8192, 1024, 1024, 8);

    // 7) BatchNorm (deterministic)
    bn_stats<<<dim3(64, 4), 256, 0, stream>>>(xbuf, psum, psq);
    bn_final<<<1, 1024, 0, stream>>>(psum, psq, gamma, beta, ab);
    bn_apply<<<2048, 256, 0, stream>>>((const float4*)xbuf, ab, (float4*)out0);
}

// Round 5
// 495.067 us; speedup vs baseline: 1.1364x; 1.1364x over previous
//
#include <hip/hip_runtime.h>
#include <hip/hip_bf16.h>
#include <stdint.h>

// ---------- types ----------
typedef __attribute__((ext_vector_type(8))) short     short8;   // 8 bf16 (raw bits)
typedef __attribute__((ext_vector_type(8))) _Float16  f16x8;    // 8 fp16
typedef __attribute__((ext_vector_type(4))) float     f32x4;
typedef __attribute__((ext_vector_type(8))) unsigned short ushort8;
typedef __attribute__((ext_vector_type(4))) unsigned short ushort4_t;

// ---------- scalar conversion helpers ----------
__device__ inline unsigned short f2bf(float f) {
    unsigned u = __float_as_uint(f);
    u += 0x7fffu + ((u >> 16) & 1u);          // RNE
    return (unsigned short)(u >> 16);
}
__device__ inline float bf2f(unsigned short h) {
    return __uint_as_float(((unsigned)h) << 16);
}
__device__ inline unsigned short f2h(float f) {
    _Float16 h = (_Float16)f;
    unsigned short r;
    __builtin_memcpy(&r, &h, 2);
    return r;
}

// ---------- async global->LDS (width 16) ----------
__device__ inline void gload16(const void* g, void* lds) {
    unsigned loff = (unsigned)(uintptr_t)lds;
    loff = __builtin_amdgcn_readfirstlane(loff);
    auto l = (__attribute__((address_space(3))) unsigned int*)(uintptr_t)loff;
    auto p = (const __attribute__((address_space(1))) unsigned int*)(uintptr_t)g;
    __builtin_amdgcn_global_load_lds(p, l, 16, 0, 0);
}

// =====================================================================
// Batched elementwise f32 -> 2-byte: y=0 key->f16, y=1 query->f16, y=2 value->bf16
// =====================================================================
__global__ void cvt3_f32_2b(const float4* __restrict__ k, const float4* __restrict__ q,
                            const float4* __restrict__ v,
                            ushort4_t* __restrict__ k16, ushort4_t* __restrict__ q16,
                            ushort4_t* __restrict__ v16, int n4) {
    const int which = blockIdx.y;
    const float4* in  = which == 0 ? k   : which == 1 ? q   : v;
    ushort4_t*    out = which == 0 ? k16 : which == 1 ? q16 : v16;
    const bool tof16 = (which < 2);
    for (int i = blockIdx.x * blockDim.x + threadIdx.x; i < n4; i += gridDim.x * blockDim.x) {
        float4 vv = in[i];
        ushort4_t r;
        if (tof16) { r.x = f2h(vv.x);  r.y = f2h(vv.y);  r.z = f2h(vv.z);  r.w = f2h(vv.w); }
        else       { r.x = f2bf(vv.x); r.y = f2bf(vv.y); r.z = f2bf(vv.z); r.w = f2bf(vv.w); }
        out[i] = r;
    }
}

// =====================================================================
// Weight transpose + convert: W[dim][dim] f32 -> WT[n][k] 2-byte
// =====================================================================
template<int TOF16>
__global__ void transpose_cvt(const float* __restrict__ W, unsigned short* __restrict__ WT, int dim) {
    __shared__ float t[32][33];
    const int bx = blockIdx.x * 32, by = blockIdx.y * 32;   // bx: n, by: k
    const int tx = threadIdx.x, ty = threadIdx.y;
#pragma unroll
    for (int i = 0; i < 4; ++i)
        t[ty + 8 * i][tx] = W[(size_t)(by + ty + 8 * i) * dim + bx + tx];
    __syncthreads();
#pragma unroll
    for (int i = 0; i < 4; ++i) {
        float v = t[tx][ty + 8 * i];
        WT[(size_t)(bx + ty + 8 * i) * dim + by + tx] = TOF16 ? f2h(v) : f2bf(v);
    }
}

// =====================================================================
// v [128][1024][64] bf16 -> vT [128][64][1024] bf16
// =====================================================================
__global__ void transpose_v(const unsigned short* __restrict__ v, unsigned short* __restrict__ vT) {
    const int bh = blockIdx.z, d0 = blockIdx.x * 32, s0 = blockIdx.y * 32;
    __shared__ unsigned short t[32][33];
    const int tx = threadIdx.x, ty = threadIdx.y;
    const size_t base = (size_t)bh << 16;
#pragma unroll
    for (int i = 0; i < 4; ++i)
        t[ty + 8 * i][tx] = v[base + (size_t)(s0 + ty + 8 * i) * 64 + d0 + tx];
    __syncthreads();
#pragma unroll
    for (int i = 0; i < 4; ++i)
        vT[base + (size_t)(d0 + ty + 8 * i) * 1024 + s0 + tx] = t[tx][ty + 8 * i];
}

// =====================================================================
// GEMM (B^T form): C[M][N] = A[M][K] * W  where Bt[n][k] = W[k][n].
// m97 structure: 128x128 tile, BK=32, 4 waves (2x2), global_load_lds w16.
// EPI 0: store 2-byte (f16/bf16 per F16IN). EPI 1: f32 store of acc+bias+resid.
// =====================================================================
template<int F16IN, int EPI>
__global__ __launch_bounds__(256, 2) void gemm_bt(
    const unsigned short* __restrict__ A,
    const unsigned short* __restrict__ Bt,
    const float* __restrict__ bias,
    unsigned short* __restrict__ C2b,
    const float* __restrict__ resid,
    float* __restrict__ Cf,
    int M, int N, int K, int nbx)
{
    // XCD-chunked bijective swizzle (gridDim.x % 8 == 0)
    const int bid = blockIdx.x;
    const int cpx = gridDim.x >> 3;
    const int swz = (bid & 7) * cpx + (bid >> 3);
    const int bm = swz / nbx, bn = swz % nbx;
    const int m0 = bm * 128, n0 = bn * 128;

    const int tid = threadIdx.x;
    const int w = tid >> 6, l = tid & 63, g = l >> 4, c = l & 15;
    const int wr = w >> 1, wc = w & 1;

    __shared__ unsigned short As[4096];   // [128][32]
    __shared__ unsigned short Bs[4096];   // [128][32]

    f32x4 acc[4][4] = {};

    const int arow = tid >> 2, acol = (tid & 3) * 8;
    const unsigned short* Ap  = A  + (size_t)(m0 + arow) * K + acol;
    const unsigned short* Ap2 = A  + (size_t)(m0 + 64 + arow) * K + acol;
    const unsigned short* Bp  = Bt + (size_t)(n0 + arow) * K + acol;
    const unsigned short* Bp2 = Bt + (size_t)(n0 + 64 + arow) * K + acol;
    unsigned short* AsW  = &As[w * 512];
    unsigned short* AsW2 = &As[2048 + w * 512];
    unsigned short* BsW  = &Bs[w * 512];
    unsigned short* BsW2 = &Bs[2048 + w * 512];

    for (int k0 = 0; k0 < K; k0 += 32) {
        gload16(Ap + k0,  AsW);
        gload16(Ap2 + k0, AsW2);
        gload16(Bp + k0,  BsW);
        gload16(Bp2 + k0, BsW2);
        asm volatile("s_waitcnt vmcnt(0)" ::: "memory");
        __syncthreads();

        if constexpr (F16IN) {
            f16x8 a[4], b[4];
#pragma unroll
            for (int mt = 0; mt < 4; ++mt)
                a[mt] = *(const f16x8*)&As[(wr * 64 + mt * 16 + c) * 32 + g * 8];
#pragma unroll
            for (int nt = 0; nt < 4; ++nt)
                b[nt] = *(const f16x8*)&Bs[(wc * 64 + nt * 16 + c) * 32 + g * 8];
#pragma unroll
            for (int mt = 0; mt < 4; ++mt)
#pragma unroll
                for (int nt = 0; nt < 4; ++nt)
                    acc[mt][nt] = __builtin_amdgcn_mfma_f32_16x16x32_f16(a[mt], b[nt], acc[mt][nt], 0, 0, 0);
        } else {
            short8 a[4], b[4];
#pragma unroll
            for (int mt = 0; mt < 4; ++mt)
                a[mt] = *(const short8*)&As[(wr * 64 + mt * 16 + c) * 32 + g * 8];
#pragma unroll
            for (int nt = 0; nt < 4; ++nt)
                b[nt] = *(const short8*)&Bs[(wc * 64 + nt * 16 + c) * 32 + g * 8];
#pragma unroll
            for (int mt = 0; mt < 4; ++mt)
#pragma unroll
                for (int nt = 0; nt < 4; ++nt)
                    acc[mt][nt] = __builtin_amdgcn_mfma_f32_16x16x32_bf16(a[mt], b[nt], acc[mt][nt], 0, 0, 0);
        }
        __syncthreads();
    }

    // epilogue
#pragma unroll
    for (int nt = 0; nt < 4; ++nt) {
        const int col = n0 + wc * 64 + nt * 16 + c;
        const float bs = bias[col];
#pragma unroll
        for (int mt = 0; mt < 4; ++mt) {
            const int row0 = m0 + wr * 64 + mt * 16 + g * 4;
#pragma unroll
            for (int r = 0; r < 4; ++r) {
                const float x = acc[mt][nt][r] + bs;
                const size_t idx = (size_t)(row0 + r) * N + col;
                if constexpr (EPI == 0) {
                    C2b[idx] = F16IN ? f2h(x) : f2bf(x);
                } else {
                    Cf[idx] = x + resid[idx];
                }
            }
        }
    }
}

// =====================================================================
// Attention v4 (= v2 base + reorder + XCD-chunk + setprio):
//  - swapped QK^T (mfma(K,Q)): lane holds P[q=c][4 consecutive kcols]/tile,
//    kept in pt[16] registers AND packed ds_write_b64 into swizzled LDS.
//  - PV runs BEFORE the attention store so its vT loads aren't queued
//    behind 16 stores in vmcnt order (stores are fire-and-forget last).
//  - XCD-chunked block mapping: each XCD owns 16 bh values -> K/vT panels
//    stay resident in one L2 across their 64 rb-blocks.
//  - s_setprio(1) around the PV MFMA cluster (T5).
// One block = (bh, 16 q-rows); 4 waves x 256 k-cols. Grid = 8192 x 1.
// =====================================================================
__global__ __launch_bounds__(256, 4) void attn_kernel(
    const unsigned short* __restrict__ qf,   // f16  [128*1024*64]
    const unsigned short* __restrict__ kf,   // f16  [128*1024*64]
    const unsigned short* __restrict__ vT,   // bf16 [128][64][1024]
    float* __restrict__ attn_out,            // f32  [128][1024][1024]
    unsigned short* __restrict__ ctx)        // bf16 [128*1024*64]
{
    // XCD-aware decode: L%8 = XCD; XCD c handles bh in [c*16, c*16+16),
    // rb fastest within a bh's 64 blocks.
    const int L = blockIdx.x;
    const int rb = (L >> 3) & 63;
    const int bh = ((L & 7) << 4) | (L >> 9);

    const int tid = threadIdx.x;
    const int w = tid >> 6, l = tid & 63, g = l >> 4, c = l & 15;
    const int n0 = w * 256;

    __shared__ unsigned short P[16 * 1024];  // 32 KB, XOR-swizzled by (row&7)<<4
    __shared__ float rs_lds[4][16];
    __shared__ float inv_lds[16];

    // Q fragment (B-operand): lane holds Q[row = rb*16 + c][d = g*8 .. +7] (+32)
    const unsigned short* qb = qf + ((size_t)bh << 16) + (size_t)(rb * 16 + c) * 64 + g * 8;
    const f16x8 q0 = *(const f16x8*)(qb);
    const f16x8 q1 = *(const f16x8*)(qb + 32);

    const unsigned short* kb = kf + ((size_t)bh << 16);
    const unsigned swzc = ((unsigned)(c & 7)) << 4;
    const unsigned prow = (unsigned)c * 2048;

    f32x4 pt[16];
    float rsum = 0.f;

    // QK^T: per t, A-operand = K rows (= attention cols) n0+t*16+c, d-chunk g*8.
    // Output: lane holds score[q = c][kcol = n0 + t*16 + g*4 + r].
#pragma unroll
    for (int t = 0; t < 16; ++t) {
        const unsigned short* kp = kb + (size_t)(n0 + t * 16 + c) * 64 + g * 8;
        const f16x8 a0 = *(const f16x8*)(kp);
        const f16x8 a1 = *(const f16x8*)(kp + 32);
        f32x4 s = {0.f, 0.f, 0.f, 0.f};
        s = __builtin_amdgcn_mfma_f32_16x16x32_f16(a0, q0, s, 0, 0, 0);
        s = __builtin_amdgcn_mfma_f32_16x16x32_f16(a1, q1, s, 0, 0, 0);

        f32x4 p;
        p[0] = __expf(s[0] * 0.5f);
        p[1] = __expf(s[1] * 0.5f);
        p[2] = __expf(s[2] * 0.5f);
        p[3] = __expf(s[3] * 0.5f);
        pt[t] = p;
        rsum += (p[0] + p[1]) + (p[2] + p[3]);

        ushort4_t pk;
        pk.x = f2bf(p[0]); pk.y = f2bf(p[1]); pk.z = f2bf(p[2]); pk.w = f2bf(p[3]);
        // row = c, byte col = n0*2 + t*32 + g*8  (4 consecutive bf16 = 8B)
        *(ushort4_t*)((char*)P + ((prow + (unsigned)(n0 * 2 + t * 32 + g * 8)) ^ swzc)) = pk;
    }

    // row-sum for row c: reduce over the 4 lane-groups (lane-id bits 4,5)
    rsum += __shfl_xor(rsum, 16);
    rsum += __shfl_xor(rsum, 32);
    if (g == 0) rs_lds[w][c] = rsum;
    __syncthreads();                          // also covers P ds_writes
    if (tid < 16)
        inv_lds[tid] = 1.0f / (rs_lds[0][tid] + rs_lds[1][tid] + rs_lds[2][tid] + rs_lds[3][tid]);
    __syncthreads();

    // ---- PV first (no older pending stores -> vT loads retire fast) ----
    // Wave w owns output cols d = w*16 .. +15, K = 1024.
    // A-frag: P[row=c][k = ks*32 + g*8 ..+7] from swizzled LDS (b128).
    // B-frag: vT[w*16 + c][ks*32 + g*8 ..+7].
    f32x4 pacc = {0.f, 0.f, 0.f, 0.f};
    const unsigned short* vb = vT + ((size_t)bh << 16) + (size_t)(w * 16 + c) * 1024;
    __builtin_amdgcn_s_setprio(1);
#pragma unroll 4
    for (int ks = 0; ks < 32; ++ks) {
        const short8 a = *(const short8*)((char*)P + ((prow + (unsigned)(ks * 64 + g * 16)) ^ swzc));
        const short8 b = *(const short8*)(vb + ks * 32 + g * 8);
        pacc = __builtin_amdgcn_mfma_f32_16x16x32_bf16(a, b, pacc, 0, 0, 0);
    }
    __builtin_amdgcn_s_setprio(0);
    unsigned short* cb = ctx + ((size_t)bh << 16) + (size_t)(rb * 16) * 64 + w * 16 + c;
#pragma unroll
    for (int r = 0; r < 4; ++r) {
        const int row = g * 4 + r;
        cb[(size_t)row * 64] = f2bf(pacc[r] * inv_lds[row]);
    }

    // ---- attention store last: registers -> HBM, nontemporal f32x4 ----
    // lane writes row (rb*16+c), cols n0 + t*16 + g*4 .. +3; the 4 g-groups
    // of 16 lanes cover full 64B lines per row.
    const float inv = inv_lds[c];
    float* ao = attn_out + ((size_t)bh << 20) + (size_t)(rb * 16 + c) * 1024 + n0 + g * 4;
#pragma unroll
    for (int t = 0; t < 16; ++t) {
        f32x4 o;
        o[0] = pt[t][0] * inv;
        o[1] = pt[t][1] * inv;
        o[2] = pt[t][2] * inv;
        o[3] = pt[t][3] * inv;
        __builtin_nontemporal_store(o, (f32x4*)(ao + t * 16));
    }
}

// =====================================================================
// BatchNorm over channels (deterministic two-level reduction)
// =====================================================================
__global__ void bn_stats(const float* __restrict__ x, float* __restrict__ psum, float* __restrict__ psq) {
    const int col = blockIdx.y * 256 + threadIdx.x;   // grid.y = 4
    const int r0 = blockIdx.x * 128;                  // grid.x = 64
    float s = 0.f, q = 0.f;
#pragma unroll 4
    for (int r = 0; r < 128; ++r) {
        const float v = x[(size_t)(r0 + r) * 1024 + col];
        s += v; q += v * v;
    }
    psum[blockIdx.x * 1024 + col] = s;
    psq [blockIdx.x * 1024 + col] = q;
}

__global__ void bn_final(const float* __restrict__ psum, const float* __restrict__ psq,
                         const float* __restrict__ gamma, const float* __restrict__ beta,
                         float* __restrict__ ab) {
    const int cidx = threadIdx.x;   // 1024 threads
    float s = 0.f, q = 0.f;
#pragma unroll 8
    for (int i = 0; i < 64; ++i) { s += psum[i * 1024 + cidx]; q += psq[i * 1024 + cidx]; }
    const float mean = s * (1.0f / 8192.0f);
    const float var  = q * (1.0f / 8192.0f) - mean * mean;
    const float a = gamma[cidx] * rsqrtf(var + 1e-5f);
    ab[cidx]        = a;
    ab[1024 + cidx] = beta[cidx] - mean * a;
}

__global__ void bn_apply(const float4* __restrict__ x4, const float* __restrict__ ab, float4* __restrict__ o4) {
    const int n4 = 2 * 1024 * 1024;
    for (int i = blockIdx.x * blockDim.x + threadIdx.x; i < n4; i += gridDim.x * blockDim.x) {
        const float4 v = x4[i];
        const int c0 = (i & 255) << 2;
        float4 r;
        r.x = v.x * ab[c0 + 0] + ab[1024 + c0 + 0];
        r.y = v.y * ab[c0 + 1] + ab[1024 + c0 + 1];
        r.z = v.z * ab[c0 + 2] + ab[1024 + c0 + 2];
        r.w = v.w * ab[c0 + 3] + ab[1024 + c0 + 3];
        o4[i] = r;
    }
}

// =====================================================================
// launch
// =====================================================================
extern "C" void kernel_launch(void* const* d_in, const int* in_sizes, int n_in,
                              void* d_out, int out_size, void* d_ws, size_t ws_size,
                              hipStream_t stream) {
    (void)in_sizes; (void)n_in; (void)out_size; (void)ws_size;

    const float* key   = (const float*)d_in[0];
    const float* value = (const float*)d_in[1];
    const float* query = (const float*)d_in[2];
    const float* Wk = (const float*)d_in[3];
    const float* bk = (const float*)d_in[4];
    const float* Wv = (const float*)d_in[5];
    const float* bv = (const float*)d_in[6];
    const float* Wq = (const float*)d_in[7];
    const float* bq = (const float*)d_in[8];
    const float* Wf = (const float*)d_in[9];
    const float* bff = (const float*)d_in[10];
    const float* gamma = (const float*)d_in[11];
    const float* beta  = (const float*)d_in[12];

    char* ws = (char*)d_ws;
    const size_t MB = 1u << 20;
    // layout (with safe overlap reuse):
    unsigned short* key16   = (unsigned short*)(ws + 0);        // dead after GEMM-k -> reused as ctx
    unsigned short* ctx     = (unsigned short*)(ws + 0);
    unsigned short* query16 = (unsigned short*)(ws + 16 * MB);  // dead after GEMM-q -+
    unsigned short* value16 = (unsigned short*)(ws + 32 * MB);  // dead after GEMM-v -+-> reused as xbuf
    float*          xbuf    = (float*)(ws + 16 * MB);           // 32 MB
    unsigned short* WkT = (unsigned short*)(ws + 48 * MB);
    unsigned short* WqT = (unsigned short*)(ws + 50 * MB);
    unsigned short* WvT = (unsigned short*)(ws + 52 * MB);
    unsigned short* WfT = (unsigned short*)(ws + 54 * MB);
    unsigned short* kbuf = (unsigned short*)(ws + 56 * MB);
    unsigned short* qbuf = (unsigned short*)(ws + 72 * MB);
    unsigned short* vbuf = (unsigned short*)(ws + 88 * MB);     // dead after transpose_v -> stats
    float* psum = (float*)(ws + 88 * MB);
    float* psq  = (float*)(ws + 88 * MB + 256 * 1024);
    float* ab   = (float*)(ws + 88 * MB + 512 * 1024);
    unsigned short* vTbuf = (unsigned short*)(ws + 104 * MB);
    // total: 120 MB

    float* out0 = (float*)d_out;            // [8M]  normalized output
    float* attn = out0 + 8388608;           // [128M] attention

    const int n4big = 2 * 1024 * 1024;      // 8M floats / 4

    // 1) input conversions (single batched launch)
    cvt3_f32_2b<<<dim3(1024, 3), 256, 0, stream>>>(
        (const float4*)key, (const float4*)query, (const float4*)value,
        (ushort4_t*)key16, (ushort4_t*)query16, (ushort4_t*)value16, n4big);

    // 2) weight transposes
    dim3 tb(32, 8), tg(32, 32);
    transpose_cvt<1><<<tg, tb, 0, stream>>>(Wk, WkT, 1024);
    transpose_cvt<1><<<tg, tb, 0, stream>>>(Wq, WqT, 1024);
    transpose_cvt<0><<<tg, tb, 0, stream>>>(Wv, WvT, 1024);
    transpose_cvt<0><<<tg, tb, 0, stream>>>(Wf, WfT, 1024);

    // 3) QKV projections (M=8192, N=1024, K=1024), f16 for q/k, bf16 for v
    gemm_bt<1, 0><<<512, 256, 0, stream>>>(key16,   WkT, bk, kbuf, nullptr, nullptr, 8192, 1024, 1024, 8);
    gemm_bt<1, 0><<<512, 256, 0, stream>>>(query16, WqT, bq, qbuf, nullptr, nullptr, 8192, 1024, 1024, 8);
    gemm_bt<0, 0><<<512, 256, 0, stream>>>(value16, WvT, bv, vbuf, nullptr, nullptr, 8192, 1024, 1024, 8);

    // 4) v -> vT per head-batch
    transpose_v<<<dim3(2, 32, 128), tb, 0, stream>>>(vbuf, vTbuf);

    // 5) attention (writes attention matrix + ctx), XCD-chunked 1-D grid
    attn_kernel<<<8192, 256, 0, stream>>>(qbuf, kbuf, vTbuf, attn, ctx);

    // 6) output projection + residual -> xbuf (f32)
    gemm_bt<0, 1><<<512, 256, 0, stream>>>(ctx, WfT, bff, nullptr, query, xbuf, 8192, 1024, 1024, 8);

    // 7) BatchNorm (deterministic)
    bn_stats<<<dim3(64, 4), 256, 0, stream>>>(xbuf, psum, psq);
    bn_final<<<1, 1024, 0, stream>>>(psum, psq, gamma, beta, ab);
    bn_apply<<<2048, 256, 0, stream>>>((const float4*)xbuf, ab, (float4*)out0);
}

// Round 6
// 467.107 us; speedup vs baseline: 1.2044x; 1.0599x over previous
//
#include <hip/hip_runtime.h>
#include <hip/hip_bf16.h>
#include <stdint.h>

// ---------- types ----------
typedef __attribute__((ext_vector_type(8))) short     short8;   // 8 bf16 (raw bits)
typedef __attribute__((ext_vector_type(8))) _Float16  f16x8;    // 8 fp16
typedef __attribute__((ext_vector_type(4))) float     f32x4;
typedef __attribute__((ext_vector_type(8))) unsigned short ushort8;
typedef __attribute__((ext_vector_type(4))) unsigned short ushort4_t;

// ---------- scalar conversion helpers ----------
__device__ inline unsigned short f2bf(float f) {
    unsigned u = __float_as_uint(f);
    u += 0x7fffu + ((u >> 16) & 1u);          // RNE
    return (unsigned short)(u >> 16);
}
__device__ inline float bf2f(unsigned short h) {
    return __uint_as_float(((unsigned)h) << 16);
}
__device__ inline unsigned short f2h(float f) {
    _Float16 h = (_Float16)f;
    unsigned short r;
    __builtin_memcpy(&r, &h, 2);
    return r;
}

// ---------- async global->LDS (width 16) ----------
__device__ inline void gload16(const void* g, void* lds) {
    unsigned loff = (unsigned)(uintptr_t)lds;
    loff = __builtin_amdgcn_readfirstlane(loff);
    auto l = (__attribute__((address_space(3))) unsigned int*)(uintptr_t)loff;
    auto p = (const __attribute__((address_space(1))) unsigned int*)(uintptr_t)g;
    __builtin_amdgcn_global_load_lds(p, l, 16, 0, 0);
}

// =====================================================================
// Batched elementwise f32 -> 2-byte: y=0 key->f16, y=1 query->f16, y=2 value->bf16
// =====================================================================
__global__ void cvt3_f32_2b(const float4* __restrict__ k, const float4* __restrict__ q,
                            const float4* __restrict__ v,
                            ushort4_t* __restrict__ k16, ushort4_t* __restrict__ q16,
                            ushort4_t* __restrict__ v16, int n4) {
    const int which = blockIdx.y;
    const float4* in  = which == 0 ? k   : which == 1 ? q   : v;
    ushort4_t*    out = which == 0 ? k16 : which == 1 ? q16 : v16;
    const bool tof16 = (which < 2);
    for (int i = blockIdx.x * blockDim.x + threadIdx.x; i < n4; i += gridDim.x * blockDim.x) {
        float4 vv = in[i];
        ushort4_t r;
        if (tof16) { r.x = f2h(vv.x);  r.y = f2h(vv.y);  r.z = f2h(vv.z);  r.w = f2h(vv.w); }
        else       { r.x = f2bf(vv.x); r.y = f2bf(vv.y); r.z = f2bf(vv.z); r.w = f2bf(vv.w); }
        out[i] = r;
    }
}

// =====================================================================
// Weight transpose + convert: W[dim][dim] f32 -> WT[n][k] 2-byte
// =====================================================================
template<int TOF16>
__global__ void transpose_cvt(const float* __restrict__ W, unsigned short* __restrict__ WT, int dim) {
    __shared__ float t[32][33];
    const int bx = blockIdx.x * 32, by = blockIdx.y * 32;   // bx: n, by: k
    const int tx = threadIdx.x, ty = threadIdx.y;
#pragma unroll
    for (int i = 0; i < 4; ++i)
        t[ty + 8 * i][tx] = W[(size_t)(by + ty + 8 * i) * dim + bx + tx];
    __syncthreads();
#pragma unroll
    for (int i = 0; i < 4; ++i) {
        float v = t[tx][ty + 8 * i];
        WT[(size_t)(bx + ty + 8 * i) * dim + by + tx] = TOF16 ? f2h(v) : f2bf(v);
    }
}

// =====================================================================
// v [128][1024][64] bf16 -> vT [128][64][1024] bf16
// =====================================================================
__global__ void transpose_v(const unsigned short* __restrict__ v, unsigned short* __restrict__ vT) {
    const int bh = blockIdx.z, d0 = blockIdx.x * 32, s0 = blockIdx.y * 32;
    __shared__ unsigned short t[32][33];
    const int tx = threadIdx.x, ty = threadIdx.y;
    const size_t base = (size_t)bh << 16;
#pragma unroll
    for (int i = 0; i < 4; ++i)
        t[ty + 8 * i][tx] = v[base + (size_t)(s0 + ty + 8 * i) * 64 + d0 + tx];
    __syncthreads();
#pragma unroll
    for (int i = 0; i < 4; ++i)
        vT[base + (size_t)(d0 + ty + 8 * i) * 1024 + s0 + tx] = t[tx][ty + 8 * i];
}

// =====================================================================
// GEMM (B^T form): C[M][N] = A[M][K] * W  where Bt[n][k] = W[k][n].
// m97 structure: 128x128 tile, BK=32, 4 waves (2x2), global_load_lds w16.
// EPI 0: store 2-byte (f16/bf16 per F16IN). EPI 1: f32 store of acc+bias+resid.
// =====================================================================
template<int F16IN, int EPI>
__global__ __launch_bounds__(256, 2) void gemm_bt(
    const unsigned short* __restrict__ A,
    const unsigned short* __restrict__ Bt,
    const float* __restrict__ bias,
    unsigned short* __restrict__ C2b,
    const float* __restrict__ resid,
    float* __restrict__ Cf,
    int M, int N, int K, int nbx)
{
    // XCD-chunked bijective swizzle (gridDim.x % 8 == 0)
    const int bid = blockIdx.x;
    const int cpx = gridDim.x >> 3;
    const int swz = (bid & 7) * cpx + (bid >> 3);
    const int bm = swz / nbx, bn = swz % nbx;
    const int m0 = bm * 128, n0 = bn * 128;

    const int tid = threadIdx.x;
    const int w = tid >> 6, l = tid & 63, g = l >> 4, c = l & 15;
    const int wr = w >> 1, wc = w & 1;

    __shared__ unsigned short As[4096];   // [128][32]
    __shared__ unsigned short Bs[4096];   // [128][32]

    f32x4 acc[4][4] = {};

    const int arow = tid >> 2, acol = (tid & 3) * 8;
    const unsigned short* Ap  = A  + (size_t)(m0 + arow) * K + acol;
    const unsigned short* Ap2 = A  + (size_t)(m0 + 64 + arow) * K + acol;
    const unsigned short* Bp  = Bt + (size_t)(n0 + arow) * K + acol;
    const unsigned short* Bp2 = Bt + (size_t)(n0 + 64 + arow) * K + acol;
    unsigned short* AsW  = &As[w * 512];
    unsigned short* AsW2 = &As[2048 + w * 512];
    unsigned short* BsW  = &Bs[w * 512];
    unsigned short* BsW2 = &Bs[2048 + w * 512];

    for (int k0 = 0; k0 < K; k0 += 32) {
        gload16(Ap + k0,  AsW);
        gload16(Ap2 + k0, AsW2);
        gload16(Bp + k0,  BsW);
        gload16(Bp2 + k0, BsW2);
        asm volatile("s_waitcnt vmcnt(0)" ::: "memory");
        __syncthreads();

        if constexpr (F16IN) {
            f16x8 a[4], b[4];
#pragma unroll
            for (int mt = 0; mt < 4; ++mt)
                a[mt] = *(const f16x8*)&As[(wr * 64 + mt * 16 + c) * 32 + g * 8];
#pragma unroll
            for (int nt = 0; nt < 4; ++nt)
                b[nt] = *(const f16x8*)&Bs[(wc * 64 + nt * 16 + c) * 32 + g * 8];
#pragma unroll
            for (int mt = 0; mt < 4; ++mt)
#pragma unroll
                for (int nt = 0; nt < 4; ++nt)
                    acc[mt][nt] = __builtin_amdgcn_mfma_f32_16x16x32_f16(a[mt], b[nt], acc[mt][nt], 0, 0, 0);
        } else {
            short8 a[4], b[4];
#pragma unroll
            for (int mt = 0; mt < 4; ++mt)
                a[mt] = *(const short8*)&As[(wr * 64 + mt * 16 + c) * 32 + g * 8];
#pragma unroll
            for (int nt = 0; nt < 4; ++nt)
                b[nt] = *(const short8*)&Bs[(wc * 64 + nt * 16 + c) * 32 + g * 8];
#pragma unroll
            for (int mt = 0; mt < 4; ++mt)
#pragma unroll
                for (int nt = 0; nt < 4; ++nt)
                    acc[mt][nt] = __builtin_amdgcn_mfma_f32_16x16x32_bf16(a[mt], b[nt], acc[mt][nt], 0, 0, 0);
        }
        __syncthreads();
    }

    // epilogue
#pragma unroll
    for (int nt = 0; nt < 4; ++nt) {
        const int col = n0 + wc * 64 + nt * 16 + c;
        const float bs = bias[col];
#pragma unroll
        for (int mt = 0; mt < 4; ++mt) {
            const int row0 = m0 + wr * 64 + mt * 16 + g * 4;
#pragma unroll
            for (int r = 0; r < 4; ++r) {
                const float x = acc[mt][nt][r] + bs;
                const size_t idx = (size_t)(row0 + r) * N + col;
                if constexpr (EPI == 0) {
                    C2b[idx] = F16IN ? f2h(x) : f2bf(x);
                } else {
                    Cf[idx] = x + resid[idx];
                }
            }
        }
    }
}

// =====================================================================
// Attention v5 = v2 body (best known, ~250us) + XCD-chunked decode ONLY.
//  - swapped QK^T (mfma(K,Q)): lane holds P[q=c][4 consecutive kcols]/tile,
//    in pt[16] regs AND packed ds_write_b64 to swizzled LDS.
//  - attention store FIRST (pt dies -> no reg pressure in PV), nontemporal.
//  - PV after, from LDS P x vT.  No setprio (4-wave lockstep: m190 regime).
//  - XCD-chunk: XCD c owns bh in [c*16, c*16+16), rb fastest -> K/vT panels
//    L2-resident (T1 mechanism; equivalent to proven chunked swizzle).
// One block = (bh, 16 q-rows); 4 waves x 256 k-cols. Grid = 8192 x 1.
// =====================================================================
__global__ __launch_bounds__(256, 4) void attn_kernel(
    const unsigned short* __restrict__ qf,   // f16  [128*1024*64]
    const unsigned short* __restrict__ kf,   // f16  [128*1024*64]
    const unsigned short* __restrict__ vT,   // bf16 [128][64][1024]
    float* __restrict__ attn_out,            // f32  [128][1024][1024]
    unsigned short* __restrict__ ctx)        // bf16 [128*1024*64]
{
    const int L = blockIdx.x;
    const int rb = (L >> 3) & 63;
    const int bh = ((L & 7) << 4) | (L >> 9);

    const int tid = threadIdx.x;
    const int w = tid >> 6, l = tid & 63, g = l >> 4, c = l & 15;
    const int n0 = w * 256;

    __shared__ unsigned short P[16 * 1024];  // 32 KB, XOR-swizzled by (row&7)<<4
    __shared__ float rs_lds[4][16];
    __shared__ float inv_lds[16];

    // Q fragment (B-operand): lane holds Q[row = rb*16 + c][d = g*8 .. +7] (+32)
    const unsigned short* qb = qf + ((size_t)bh << 16) + (size_t)(rb * 16 + c) * 64 + g * 8;
    const f16x8 q0 = *(const f16x8*)(qb);
    const f16x8 q1 = *(const f16x8*)(qb + 32);

    const unsigned short* kb = kf + ((size_t)bh << 16);
    const unsigned swzc = ((unsigned)(c & 7)) << 4;
    const unsigned prow = (unsigned)c * 2048;

    f32x4 pt[16];
    float rsum = 0.f;

    // QK^T: per t, A-operand = K rows (= attention cols) n0+t*16+c, d-chunk g*8.
    // Output: lane holds score[q = c][kcol = n0 + t*16 + g*4 + r].
#pragma unroll
    for (int t = 0; t < 16; ++t) {
        const unsigned short* kp = kb + (size_t)(n0 + t * 16 + c) * 64 + g * 8;
        const f16x8 a0 = *(const f16x8*)(kp);
        const f16x8 a1 = *(const f16x8*)(kp + 32);
        f32x4 s = {0.f, 0.f, 0.f, 0.f};
        s = __builtin_amdgcn_mfma_f32_16x16x32_f16(a0, q0, s, 0, 0, 0);
        s = __builtin_amdgcn_mfma_f32_16x16x32_f16(a1, q1, s, 0, 0, 0);

        f32x4 p;
        p[0] = __expf(s[0] * 0.5f);
        p[1] = __expf(s[1] * 0.5f);
        p[2] = __expf(s[2] * 0.5f);
        p[3] = __expf(s[3] * 0.5f);
        pt[t] = p;
        rsum += (p[0] + p[1]) + (p[2] + p[3]);

        ushort4_t pk;
        pk.x = f2bf(p[0]); pk.y = f2bf(p[1]); pk.z = f2bf(p[2]); pk.w = f2bf(p[3]);
        // row = c, byte col = n0*2 + t*32 + g*8  (4 consecutive bf16 = 8B)
        *(ushort4_t*)((char*)P + ((prow + (unsigned)(n0 * 2 + t * 32 + g * 8)) ^ swzc)) = pk;
    }

    // row-sum for row c: reduce over the 4 lane-groups (lane-id bits 4,5)
    rsum += __shfl_xor(rsum, 16);
    rsum += __shfl_xor(rsum, 32);
    if (g == 0) rs_lds[w][c] = rsum;
    __syncthreads();                          // also covers P ds_writes
    if (tid < 16)
        inv_lds[tid] = 1.0f / (rs_lds[0][tid] + rs_lds[1][tid] + rs_lds[2][tid] + rs_lds[3][tid]);
    __syncthreads();

    // attention store: registers -> HBM, nontemporal f32x4 (pt dies here).
    const float inv = inv_lds[c];
    float* ao = attn_out + ((size_t)bh << 20) + (size_t)(rb * 16 + c) * 1024 + n0 + g * 4;
#pragma unroll
    for (int t = 0; t < 16; ++t) {
        f32x4 o;
        o[0] = pt[t][0] * inv;
        o[1] = pt[t][1] * inv;
        o[2] = pt[t][2] * inv;
        o[3] = pt[t][3] * inv;
        __builtin_nontemporal_store(o, (f32x4*)(ao + t * 16));
    }

    // PV: wave w owns output cols d = w*16 .. +15, K = 1024.
    // A-frag: P[row=c][k = ks*32 + g*8 ..+7] from swizzled LDS (b128).
    // B-frag: vT[w*16 + c][ks*32 + g*8 ..+7].
    f32x4 pacc = {0.f, 0.f, 0.f, 0.f};
    const unsigned short* vb = vT + ((size_t)bh << 16) + (size_t)(w * 16 + c) * 1024;
#pragma unroll 4
    for (int ks = 0; ks < 32; ++ks) {
        const short8 a = *(const short8*)((char*)P + ((prow + (unsigned)(ks * 64 + g * 16)) ^ swzc));
        const short8 b = *(const short8*)(vb + ks * 32 + g * 8);
        pacc = __builtin_amdgcn_mfma_f32_16x16x32_bf16(a, b, pacc, 0, 0, 0);
    }
    unsigned short* cb = ctx + ((size_t)bh << 16) + (size_t)(rb * 16) * 64 + w * 16 + c;
#pragma unroll
    for (int r = 0; r < 4; ++r) {
        const int row = g * 4 + r;
        cb[(size_t)row * 64] = f2bf(pacc[r] * inv_lds[row]);
    }
}

// =====================================================================
// BatchNorm over channels (deterministic two-level reduction)
// =====================================================================
__global__ void bn_stats(const float* __restrict__ x, float* __restrict__ psum, float* __restrict__ psq) {
    const int col = blockIdx.y * 256 + threadIdx.x;   // grid.y = 4
    const int r0 = blockIdx.x * 128;                  // grid.x = 64
    float s = 0.f, q = 0.f;
#pragma unroll 4
    for (int r = 0; r < 128; ++r) {
        const float v = x[(size_t)(r0 + r) * 1024 + col];
        s += v; q += v * v;
    }
    psum[blockIdx.x * 1024 + col] = s;
    psq [blockIdx.x * 1024 + col] = q;
}

__global__ void bn_final(const float* __restrict__ psum, const float* __restrict__ psq,
                         const float* __restrict__ gamma, const float* __restrict__ beta,
                         float* __restrict__ ab) {
    const int cidx = threadIdx.x;   // 1024 threads
    float s = 0.f, q = 0.f;
#pragma unroll 8
    for (int i = 0; i < 64; ++i) { s += psum[i * 1024 + cidx]; q += psq[i * 1024 + cidx]; }
    const float mean = s * (1.0f / 8192.0f);
    const float var  = q * (1.0f / 8192.0f) - mean * mean;
    const float a = gamma[cidx] * rsqrtf(var + 1e-5f);
    ab[cidx]        = a;
    ab[1024 + cidx] = beta[cidx] - mean * a;
}

__global__ void bn_apply(const float4* __restrict__ x4, const float* __restrict__ ab, float4* __restrict__ o4) {
    const int n4 = 2 * 1024 * 1024;
    for (int i = blockIdx.x * blockDim.x + threadIdx.x; i < n4; i += gridDim.x * blockDim.x) {
        const float4 v = x4[i];
        const int c0 = (i & 255) << 2;
        float4 r;
        r.x = v.x * ab[c0 + 0] + ab[1024 + c0 + 0];
        r.y = v.y * ab[c0 + 1] + ab[1024 + c0 + 1];
        r.z = v.z * ab[c0 + 2] + ab[1024 + c0 + 2];
        r.w = v.w * ab[c0 + 3] + ab[1024 + c0 + 3];
        o4[i] = r;
    }
}

// =====================================================================
// launch
// =====================================================================
extern "C" void kernel_launch(void* const* d_in, const int* in_sizes, int n_in,
                              void* d_out, int out_size, void* d_ws, size_t ws_size,
                              hipStream_t stream) {
    (void)in_sizes; (void)n_in; (void)out_size; (void)ws_size;

    const float* key   = (const float*)d_in[0];
    const float* value = (const float*)d_in[1];
    const float* query = (const float*)d_in[2];
    const float* Wk = (const float*)d_in[3];
    const float* bk = (const float*)d_in[4];
    const float* Wv = (const float*)d_in[5];
    const float* bv = (const float*)d_in[6];
    const float* Wq = (const float*)d_in[7];
    const float* bq = (const float*)d_in[8];
    const float* Wf = (const float*)d_in[9];
    const float* bff = (const float*)d_in[10];
    const float* gamma = (const float*)d_in[11];
    const float* beta  = (const float*)d_in[12];

    char* ws = (char*)d_ws;
    const size_t MB = 1u << 20;
    // layout (with safe overlap reuse):
    unsigned short* key16   = (unsigned short*)(ws + 0);        // dead after GEMM-k -> reused as ctx
    unsigned short* ctx     = (unsigned short*)(ws + 0);
    unsigned short* query16 = (unsigned short*)(ws + 16 * MB);  // dead after GEMM-q -+
    unsigned short* value16 = (unsigned short*)(ws + 32 * MB);  // dead after GEMM-v -+-> reused as xbuf
    float*          xbuf    = (float*)(ws + 16 * MB);           // 32 MB
    unsigned short* WkT = (unsigned short*)(ws + 48 * MB);
    unsigned short* WqT = (unsigned short*)(ws + 50 * MB);
    unsigned short* WvT = (unsigned short*)(ws + 52 * MB);
    unsigned short* WfT = (unsigned short*)(ws + 54 * MB);
    unsigned short* kbuf = (unsigned short*)(ws + 56 * MB);
    unsigned short* qbuf = (unsigned short*)(ws + 72 * MB);
    unsigned short* vbuf = (unsigned short*)(ws + 88 * MB);     // dead after transpose_v -> stats
    float* psum = (float*)(ws + 88 * MB);
    float* psq  = (float*)(ws + 88 * MB + 256 * 1024);
    float* ab   = (float*)(ws + 88 * MB + 512 * 1024);
    unsigned short* vTbuf = (unsigned short*)(ws + 104 * MB);
    // total: 120 MB

    float* out0 = (float*)d_out;            // [8M]  normalized output
    float* attn = out0 + 8388608;           // [128M] attention

    const int n4big = 2 * 1024 * 1024;      // 8M floats / 4

    // 1) input conversions (single batched launch)
    cvt3_f32_2b<<<dim3(1024, 3), 256, 0, stream>>>(
        (const float4*)key, (const float4*)query, (const float4*)value,
        (ushort4_t*)key16, (ushort4_t*)query16, (ushort4_t*)value16, n4big);

    // 2) weight transposes
    dim3 tb(32, 8), tg(32, 32);
    transpose_cvt<1><<<tg, tb, 0, stream>>>(Wk, WkT, 1024);
    transpose_cvt<1><<<tg, tb, 0, stream>>>(Wq, WqT, 1024);
    transpose_cvt<0><<<tg, tb, 0, stream>>>(Wv, WvT, 1024);
    transpose_cvt<0><<<tg, tb, 0, stream>>>(Wf, WfT, 1024);

    // 3) QKV projections (M=8192, N=1024, K=1024), f16 for q/k, bf16 for v
    gemm_bt<1, 0><<<512, 256, 0, stream>>>(key16,   WkT, bk, kbuf, nullptr, nullptr, 8192, 1024, 1024, 8);
    gemm_bt<1, 0><<<512, 256, 0, stream>>>(query16, WqT, bq, qbuf, nullptr, nullptr, 8192, 1024, 1024, 8);
    gemm_bt<0, 0><<<512, 256, 0, stream>>>(value16, WvT, bv, vbuf, nullptr, nullptr, 8192, 1024, 1024, 8);

    // 4) v -> vT per head-batch
    transpose_v<<<dim3(2, 32, 128), tb, 0, stream>>>(vbuf, vTbuf);

    // 5) attention (writes attention matrix + ctx), XCD-chunked 1-D grid
    attn_kernel<<<8192, 256, 0, stream>>>(qbuf, kbuf, vTbuf, attn, ctx);

    // 6) output projection + residual -> xbuf (f32)
    gemm_bt<0, 1><<<512, 256, 0, stream>>>(ctx, WfT, bff, nullptr, query, xbuf, 8192, 1024, 1024, 8);

    // 7) BatchNorm (deterministic)
    bn_stats<<<dim3(64, 4), 256, 0, stream>>>(xbuf, psum, psq);
    bn_final<<<1, 1024, 0, stream>>>(psum, psq, gamma, beta, ab);
    bn_apply<<<2048, 256, 0, stream>>>((const float4*)xbuf, ab, (float4*)out0);
}

// Round 7
// 458.878 us; speedup vs baseline: 1.2260x; 1.0179x over previous
//
#include <hip/hip_runtime.h>
#include <hip/hip_bf16.h>
#include <stdint.h>

// ---------- types ----------
typedef __attribute__((ext_vector_type(8))) short     short8;   // 8 bf16 (raw bits)
typedef __attribute__((ext_vector_type(8))) _Float16  f16x8;    // 8 fp16
typedef __attribute__((ext_vector_type(4))) float     f32x4;
typedef __attribute__((ext_vector_type(8))) unsigned short ushort8;
typedef __attribute__((ext_vector_type(4))) unsigned short ushort4_t;

// ---------- scalar conversion helpers ----------
__device__ inline unsigned short f2bf(float f) {
    unsigned u = __float_as_uint(f);
    u += 0x7fffu + ((u >> 16) & 1u);          // RNE
    return (unsigned short)(u >> 16);
}
__device__ inline float bf2f(unsigned short h) {
    return __uint_as_float(((unsigned)h) << 16);
}
__device__ inline unsigned short f2h(float f) {
    _Float16 h = (_Float16)f;
    unsigned short r;
    __builtin_memcpy(&r, &h, 2);
    return r;
}

// ---------- async global->LDS (width 16) ----------
__device__ inline void gload16(const void* g, void* lds) {
    unsigned loff = (unsigned)(uintptr_t)lds;
    loff = __builtin_amdgcn_readfirstlane(loff);
    auto l = (__attribute__((address_space(3))) unsigned int*)(uintptr_t)loff;
    auto p = (const __attribute__((address_space(1))) unsigned int*)(uintptr_t)g;
    __builtin_amdgcn_global_load_lds(p, l, 16, 0, 0);
}

// =====================================================================
// Batched elementwise f32 -> 2-byte: y=0 key->f16, y=1 query->f16, y=2 value->bf16
// =====================================================================
__global__ void cvt3_f32_2b(const float4* __restrict__ k, const float4* __restrict__ q,
                            const float4* __restrict__ v,
                            ushort4_t* __restrict__ k16, ushort4_t* __restrict__ q16,
                            ushort4_t* __restrict__ v16, int n4) {
    const int which = blockIdx.y;
    const float4* in  = which == 0 ? k   : which == 1 ? q   : v;
    ushort4_t*    out = which == 0 ? k16 : which == 1 ? q16 : v16;
    const bool tof16 = (which < 2);
    for (int i = blockIdx.x * blockDim.x + threadIdx.x; i < n4; i += gridDim.x * blockDim.x) {
        float4 vv = in[i];
        ushort4_t r;
        if (tof16) { r.x = f2h(vv.x);  r.y = f2h(vv.y);  r.z = f2h(vv.z);  r.w = f2h(vv.w); }
        else       { r.x = f2bf(vv.x); r.y = f2bf(vv.y); r.z = f2bf(vv.z); r.w = f2bf(vv.w); }
        out[i] = r;
    }
}

// =====================================================================
// Weight transpose + convert: W[dim][dim] f32 -> WT[n][k] 2-byte
// =====================================================================
template<int TOF16>
__global__ void transpose_cvt(const float* __restrict__ W, unsigned short* __restrict__ WT, int dim) {
    __shared__ float t[32][33];
    const int bx = blockIdx.x * 32, by = blockIdx.y * 32;   // bx: n, by: k
    const int tx = threadIdx.x, ty = threadIdx.y;
#pragma unroll
    for (int i = 0; i < 4; ++i)
        t[ty + 8 * i][tx] = W[(size_t)(by + ty + 8 * i) * dim + bx + tx];
    __syncthreads();
#pragma unroll
    for (int i = 0; i < 4; ++i) {
        float v = t[tx][ty + 8 * i];
        WT[(size_t)(bx + ty + 8 * i) * dim + by + tx] = TOF16 ? f2h(v) : f2bf(v);
    }
}

// =====================================================================
// v [128][1024][64] bf16 -> vT [128][64][1024] bf16
// =====================================================================
__global__ void transpose_v(const unsigned short* __restrict__ v, unsigned short* __restrict__ vT) {
    const int bh = blockIdx.z, d0 = blockIdx.x * 32, s0 = blockIdx.y * 32;
    __shared__ unsigned short t[32][33];
    const int tx = threadIdx.x, ty = threadIdx.y;
    const size_t base = (size_t)bh << 16;
#pragma unroll
    for (int i = 0; i < 4; ++i)
        t[ty + 8 * i][tx] = v[base + (size_t)(s0 + ty + 8 * i) * 64 + d0 + tx];
    __syncthreads();
#pragma unroll
    for (int i = 0; i < 4; ++i)
        vT[base + (size_t)(d0 + ty + 8 * i) * 1024 + s0 + tx] = t[tx][ty + 8 * i];
}

// =====================================================================
// GEMM (B^T form): C[M][N] = A[M][K] * W  where Bt[n][k] = W[k][n].
// m97 structure: 128x128 tile, BK=32, 4 waves (2x2), global_load_lds w16.
// EPI 0: store 2-byte (f16/bf16 per F16IN). EPI 1: f32 store of acc+bias+resid.
// =====================================================================
template<int F16IN, int EPI>
__global__ __launch_bounds__(256, 2) void gemm_bt(
    const unsigned short* __restrict__ A,
    const unsigned short* __restrict__ Bt,
    const float* __restrict__ bias,
    unsigned short* __restrict__ C2b,
    const float* __restrict__ resid,
    float* __restrict__ Cf,
    int M, int N, int K, int nbx)
{
    // XCD-chunked bijective swizzle (gridDim.x % 8 == 0)
    const int bid = blockIdx.x;
    const int cpx = gridDim.x >> 3;
    const int swz = (bid & 7) * cpx + (bid >> 3);
    const int bm = swz / nbx, bn = swz % nbx;
    const int m0 = bm * 128, n0 = bn * 128;

    const int tid = threadIdx.x;
    const int w = tid >> 6, l = tid & 63, g = l >> 4, c = l & 15;
    const int wr = w >> 1, wc = w & 1;

    __shared__ unsigned short As[4096];   // [128][32]
    __shared__ unsigned short Bs[4096];   // [128][32]

    f32x4 acc[4][4] = {};

    const int arow = tid >> 2, acol = (tid & 3) * 8;
    const unsigned short* Ap  = A  + (size_t)(m0 + arow) * K + acol;
    const unsigned short* Ap2 = A  + (size_t)(m0 + 64 + arow) * K + acol;
    const unsigned short* Bp  = Bt + (size_t)(n0 + arow) * K + acol;
    const unsigned short* Bp2 = Bt + (size_t)(n0 + 64 + arow) * K + acol;
    unsigned short* AsW  = &As[w * 512];
    unsigned short* AsW2 = &As[2048 + w * 512];
    unsigned short* BsW  = &Bs[w * 512];
    unsigned short* BsW2 = &Bs[2048 + w * 512];

    for (int k0 = 0; k0 < K; k0 += 32) {
        gload16(Ap + k0,  AsW);
        gload16(Ap2 + k0, AsW2);
        gload16(Bp + k0,  BsW);
        gload16(Bp2 + k0, BsW2);
        asm volatile("s_waitcnt vmcnt(0)" ::: "memory");
        __syncthreads();

        if constexpr (F16IN) {
            f16x8 a[4], b[4];
#pragma unroll
            for (int mt = 0; mt < 4; ++mt)
                a[mt] = *(const f16x8*)&As[(wr * 64 + mt * 16 + c) * 32 + g * 8];
#pragma unroll
            for (int nt = 0; nt < 4; ++nt)
                b[nt] = *(const f16x8*)&Bs[(wc * 64 + nt * 16 + c) * 32 + g * 8];
#pragma unroll
            for (int mt = 0; mt < 4; ++mt)
#pragma unroll
                for (int nt = 0; nt < 4; ++nt)
                    acc[mt][nt] = __builtin_amdgcn_mfma_f32_16x16x32_f16(a[mt], b[nt], acc[mt][nt], 0, 0, 0);
        } else {
            short8 a[4], b[4];
#pragma unroll
            for (int mt = 0; mt < 4; ++mt)
                a[mt] = *(const short8*)&As[(wr * 64 + mt * 16 + c) * 32 + g * 8];
#pragma unroll
            for (int nt = 0; nt < 4; ++nt)
                b[nt] = *(const short8*)&Bs[(wc * 64 + nt * 16 + c) * 32 + g * 8];
#pragma unroll
            for (int mt = 0; mt < 4; ++mt)
#pragma unroll
                for (int nt = 0; nt < 4; ++nt)
                    acc[mt][nt] = __builtin_amdgcn_mfma_f32_16x16x32_bf16(a[mt], b[nt], acc[mt][nt], 0, 0, 0);
        }
        __syncthreads();
    }

    // epilogue
#pragma unroll
    for (int nt = 0; nt < 4; ++nt) {
        const int col = n0 + wc * 64 + nt * 16 + c;
        const float bs = bias[col];
#pragma unroll
        for (int mt = 0; mt < 4; ++mt) {
            const int row0 = m0 + wr * 64 + mt * 16 + g * 4;
#pragma unroll
            for (int r = 0; r < 4; ++r) {
                const float x = acc[mt][nt][r] + bs;
                const size_t idx = (size_t)(row0 + r) * N + col;
                if constexpr (EPI == 0) {
                    C2b[idx] = F16IN ? f2h(x) : f2bf(x);
                } else {
                    Cf[idx] = x + resid[idx];
                }
            }
        }
    }
}

// =====================================================================
// Attention v6 = v5 + store/PV interleave:
//  - swapped QK^T (mfma(K,Q)); P kept as PACKED BF16 pks[16] (32 VGPR,
//    not f32 pt[16]=64) AND ds_write_b64 to swizzled LDS for PV A-frags.
//  - PV loop interleaves ONE nontemporal attention store every other
//    iteration: the NT write drain (the per-CU HBM-write floor) overlaps
//    PV's MFMA + vT L2 reads instead of serializing before them. Stores
//    depend only on pks/inv, so in-order vmcnt retirement never delays
//    the b-load waits feeding MFMA.
//  - XCD-chunk decode (kept from v5); NT stores protect L2 (kept).
// One block = (bh, 16 q-rows); 4 waves x 256 k-cols. Grid = 8192 x 1.
// =====================================================================
__global__ __launch_bounds__(256, 4) void attn_kernel(
    const unsigned short* __restrict__ qf,   // f16  [128*1024*64]
    const unsigned short* __restrict__ kf,   // f16  [128*1024*64]
    const unsigned short* __restrict__ vT,   // bf16 [128][64][1024]
    float* __restrict__ attn_out,            // f32  [128][1024][1024]
    unsigned short* __restrict__ ctx)        // bf16 [128*1024*64]
{
    const int L = blockIdx.x;
    const int rb = (L >> 3) & 63;
    const int bh = ((L & 7) << 4) | (L >> 9);

    const int tid = threadIdx.x;
    const int w = tid >> 6, l = tid & 63, g = l >> 4, c = l & 15;
    const int n0 = w * 256;

    __shared__ unsigned short P[16 * 1024];  // 32 KB, XOR-swizzled by (row&7)<<4
    __shared__ float rs_lds[4][16];
    __shared__ float inv_lds[16];

    // Q fragment (B-operand): lane holds Q[row = rb*16 + c][d = g*8 .. +7] (+32)
    const unsigned short* qb = qf + ((size_t)bh << 16) + (size_t)(rb * 16 + c) * 64 + g * 8;
    const f16x8 q0 = *(const f16x8*)(qb);
    const f16x8 q1 = *(const f16x8*)(qb + 32);

    const unsigned short* kb = kf + ((size_t)bh << 16);
    const unsigned swzc = ((unsigned)(c & 7)) << 4;
    const unsigned prow = (unsigned)c * 2048;

    ushort4_t pks[16];
    float rsum = 0.f;

    // QK^T: per t, A-operand = K rows (= attention cols) n0+t*16+c, d-chunk g*8.
    // Output: lane holds score[q = c][kcol = n0 + t*16 + g*4 + r].
#pragma unroll
    for (int t = 0; t < 16; ++t) {
        const unsigned short* kp = kb + (size_t)(n0 + t * 16 + c) * 64 + g * 8;
        const f16x8 a0 = *(const f16x8*)(kp);
        const f16x8 a1 = *(const f16x8*)(kp + 32);
        f32x4 s = {0.f, 0.f, 0.f, 0.f};
        s = __builtin_amdgcn_mfma_f32_16x16x32_f16(a0, q0, s, 0, 0, 0);
        s = __builtin_amdgcn_mfma_f32_16x16x32_f16(a1, q1, s, 0, 0, 0);

        const float p0 = __expf(s[0] * 0.5f);
        const float p1 = __expf(s[1] * 0.5f);
        const float p2 = __expf(s[2] * 0.5f);
        const float p3 = __expf(s[3] * 0.5f);
        rsum += (p0 + p1) + (p2 + p3);

        ushort4_t pk;
        pk.x = f2bf(p0); pk.y = f2bf(p1); pk.z = f2bf(p2); pk.w = f2bf(p3);
        pks[t] = pk;
        // row = c, byte col = n0*2 + t*32 + g*8  (4 consecutive bf16 = 8B)
        *(ushort4_t*)((char*)P + ((prow + (unsigned)(n0 * 2 + t * 32 + g * 8)) ^ swzc)) = pk;
    }

    // row-sum for row c: reduce over the 4 lane-groups (lane-id bits 4,5)
    rsum += __shfl_xor(rsum, 16);
    rsum += __shfl_xor(rsum, 32);
    if (g == 0) rs_lds[w][c] = rsum;
    __syncthreads();                          // also covers P ds_writes
    if (tid < 16)
        inv_lds[tid] = 1.0f / (rs_lds[0][tid] + rs_lds[1][tid] + rs_lds[2][tid] + rs_lds[3][tid]);
    __syncthreads();

    // PV with interleaved attention stores.
    // PV: wave w owns output cols d = w*16 .. +15, K = 1024.
    //   A-frag: P[row=c][k = ks*32 + g*8 ..+7] from swizzled LDS (b128).
    //   B-frag: vT[w*16 + c][ks*32 + g*8 ..+7].
    // Store: lane writes attn row (rb*16+c), cols n0 + t*16 + g*4 .. +3;
    //   the 4 g-groups of 16 lanes cover full 64B lines per row.
    const float inv = inv_lds[c];
    float* ao = attn_out + ((size_t)bh << 20) + (size_t)(rb * 16 + c) * 1024 + n0 + g * 4;
    f32x4 pacc = {0.f, 0.f, 0.f, 0.f};
    const unsigned short* vb = vT + ((size_t)bh << 16) + (size_t)(w * 16 + c) * 1024;
#pragma unroll
    for (int ks = 0; ks < 32; ++ks) {
        const short8 a = *(const short8*)((char*)P + ((prow + (unsigned)(ks * 64 + g * 16)) ^ swzc));
        const short8 b = *(const short8*)(vb + ks * 32 + g * 8);
        pacc = __builtin_amdgcn_mfma_f32_16x16x32_bf16(a, b, pacc, 0, 0, 0);
        if (ks & 1) {
            const int t = ks >> 1;
            const ushort4_t pk = pks[t];
            f32x4 o;
            o[0] = bf2f(pk.x) * inv;
            o[1] = bf2f(pk.y) * inv;
            o[2] = bf2f(pk.z) * inv;
            o[3] = bf2f(pk.w) * inv;
            __builtin_nontemporal_store(o, (f32x4*)(ao + t * 16));
        }
    }
    unsigned short* cb = ctx + ((size_t)bh << 16) + (size_t)(rb * 16) * 64 + w * 16 + c;
#pragma unroll
    for (int r = 0; r < 4; ++r) {
        const int row = g * 4 + r;
        cb[(size_t)row * 64] = f2bf(pacc[r] * inv_lds[row]);
    }
}

// =====================================================================
// BatchNorm over channels (deterministic two-level reduction)
// =====================================================================
__global__ void bn_stats(const float* __restrict__ x, float* __restrict__ psum, float* __restrict__ psq) {
    const int col = blockIdx.y * 256 + threadIdx.x;   // grid.y = 4
    const int r0 = blockIdx.x * 128;                  // grid.x = 64
    float s = 0.f, q = 0.f;
#pragma unroll 4
    for (int r = 0; r < 128; ++r) {
        const float v = x[(size_t)(r0 + r) * 1024 + col];
        s += v; q += v * v;
    }
    psum[blockIdx.x * 1024 + col] = s;
    psq [blockIdx.x * 1024 + col] = q;
}

__global__ void bn_final(const float* __restrict__ psum, const float* __restrict__ psq,
                         const float* __restrict__ gamma, const float* __restrict__ beta,
                         float* __restrict__ ab) {
    const int cidx = threadIdx.x;   // 1024 threads
    float s = 0.f, q = 0.f;
#pragma unroll 8
    for (int i = 0; i < 64; ++i) { s += psum[i * 1024 + cidx]; q += psq[i * 1024 + cidx]; }
    const float mean = s * (1.0f / 8192.0f);
    const float var  = q * (1.0f / 8192.0f) - mean * mean;
    const float a = gamma[cidx] * rsqrtf(var + 1e-5f);
    ab[cidx]        = a;
    ab[1024 + cidx] = beta[cidx] - mean * a;
}

__global__ void bn_apply(const float4* __restrict__ x4, const float* __restrict__ ab, float4* __restrict__ o4) {
    const int n4 = 2 * 1024 * 1024;
    for (int i = blockIdx.x * blockDim.x + threadIdx.x; i < n4; i += gridDim.x * blockDim.x) {
        const float4 v = x4[i];
        const int c0 = (i & 255) << 2;
        float4 r;
        r.x = v.x * ab[c0 + 0] + ab[1024 + c0 + 0];
        r.y = v.y * ab[c0 + 1] + ab[1024 + c0 + 1];
        r.z = v.z * ab[c0 + 2] + ab[1024 + c0 + 2];
        r.w = v.w * ab[c0 + 3] + ab[1024 + c0 + 3];
        o4[i] = r;
    }
}

// =====================================================================
// launch
// =====================================================================
extern "C" void kernel_launch(void* const* d_in, const int* in_sizes, int n_in,
                              void* d_out, int out_size, void* d_ws, size_t ws_size,
                              hipStream_t stream) {
    (void)in_sizes; (void)n_in; (void)out_size; (void)ws_size;

    const float* key   = (const float*)d_in[0];
    const float* value = (const float*)d_in[1];
    const float* query = (const float*)d_in[2];
    const float* Wk = (const float*)d_in[3];
    const float* bk = (const float*)d_in[4];
    const float* Wv = (const float*)d_in[5];
    const float* bv = (const float*)d_in[6];
    const float* Wq = (const float*)d_in[7];
    const float* bq = (const float*)d_in[8];
    const float* Wf = (const float*)d_in[9];
    const float* bff = (const float*)d_in[10];
    const float* gamma = (const float*)d_in[11];
    const float* beta  = (const float*)d_in[12];

    char* ws = (char*)d_ws;
    const size_t MB = 1u << 20;
    // layout (with safe overlap reuse):
    unsigned short* key16   = (unsigned short*)(ws + 0);        // dead after GEMM-k -> reused as ctx
    unsigned short* ctx     = (unsigned short*)(ws + 0);
    unsigned short* query16 = (unsigned short*)(ws + 16 * MB);  // dead after GEMM-q -+
    unsigned short* value16 = (unsigned short*)(ws + 32 * MB);  // dead after GEMM-v -+-> reused as xbuf
    float*          xbuf    = (float*)(ws + 16 * MB);           // 32 MB
    unsigned short* WkT = (unsigned short*)(ws + 48 * MB);
    unsigned short* WqT = (unsigned short*)(ws + 50 * MB);
    unsigned short* WvT = (unsigned short*)(ws + 52 * MB);
    unsigned short* WfT = (unsigned short*)(ws + 54 * MB);
    unsigned short* kbuf = (unsigned short*)(ws + 56 * MB);
    unsigned short* qbuf = (unsigned short*)(ws + 72 * MB);
    unsigned short* vbuf = (unsigned short*)(ws + 88 * MB);     // dead after transpose_v -> stats
    float* psum = (float*)(ws + 88 * MB);
    float* psq  = (float*)(ws + 88 * MB + 256 * 1024);
    float* ab   = (float*)(ws + 88 * MB + 512 * 1024);
    unsigned short* vTbuf = (unsigned short*)(ws + 104 * MB);
    // total: 120 MB

    float* out0 = (float*)d_out;            // [8M]  normalized output
    float* attn = out0 + 8388608;           // [128M] attention

    const int n4big = 2 * 1024 * 1024;      // 8M floats / 4

    // 1) input conversions (single batched launch)
    cvt3_f32_2b<<<dim3(1024, 3), 256, 0, stream>>>(
        (const float4*)key, (const float4*)query, (const float4*)value,
        (ushort4_t*)key16, (ushort4_t*)query16, (ushort4_t*)value16, n4big);

    // 2) weight transposes
    dim3 tb(32, 8), tg(32, 32);
    transpose_cvt<1><<<tg, tb, 0, stream>>>(Wk, WkT, 1024);
    transpose_cvt<1><<<tg, tb, 0, stream>>>(Wq, WqT, 1024);
    transpose_cvt<0><<<tg, tb, 0, stream>>>(Wv, WvT, 1024);
    transpose_cvt<0><<<tg, tb, 0, stream>>>(Wf, WfT, 1024);

    // 3) QKV projections (M=8192, N=1024, K=1024), f16 for q/k, bf16 for v
    gemm_bt<1, 0><<<512, 256, 0, stream>>>(key16,   WkT, bk, kbuf, nullptr, nullptr, 8192, 1024, 1024, 8);
    gemm_bt<1, 0><<<512, 256, 0, stream>>>(query16, WqT, bq, qbuf, nullptr, nullptr, 8192, 1024, 1024, 8);
    gemm_bt<0, 0><<<512, 256, 0, stream>>>(value16, WvT, bv, vbuf, nullptr, nullptr, 8192, 1024, 1024, 8);

    // 4) v -> vT per head-batch
    transpose_v<<<dim3(2, 32, 128), tb, 0, stream>>>(vbuf, vTbuf);

    // 5) attention (writes attention matrix + ctx), XCD-chunked 1-D grid
    attn_kernel<<<8192, 256, 0, stream>>>(qbuf, kbuf, vTbuf, attn, ctx);

    // 6) output projection + residual -> xbuf (f32)
    gemm_bt<0, 1><<<512, 256, 0, stream>>>(ctx, WfT, bff, nullptr, query, xbuf, 8192, 1024, 1024, 8);

    // 7) BatchNorm (deterministic)
    bn_stats<<<dim3(64, 4), 256, 0, stream>>>(xbuf, psum, psq);
    bn_final<<<1, 1024, 0, stream>>>(psum, psq, gamma, beta, ab);
    bn_apply<<<2048, 256, 0, stream>>>((const float4*)xbuf, ab, (float4*)out0);
}

// Round 8
// 447.557 us; speedup vs baseline: 1.2570x; 1.0253x over previous
//
#include <hip/hip_runtime.h>
#include <hip/hip_bf16.h>
#include <stdint.h>

// ---------- types ----------
typedef __attribute__((ext_vector_type(8))) short     short8;   // 8 bf16 (raw bits)
typedef __attribute__((ext_vector_type(8))) _Float16  f16x8;    // 8 fp16
typedef __attribute__((ext_vector_type(4))) float     f32x4;
typedef __attribute__((ext_vector_type(8))) unsigned short ushort8;
typedef __attribute__((ext_vector_type(4))) unsigned short ushort4_t;

// ---------- scalar conversion helpers ----------
__device__ inline unsigned short f2bf(float f) {
    unsigned u = __float_as_uint(f);
    u += 0x7fffu + ((u >> 16) & 1u);          // RNE
    return (unsigned short)(u >> 16);
}
__device__ inline float bf2f(unsigned short h) {
    return __uint_as_float(((unsigned)h) << 16);
}
__device__ inline unsigned short f2h(float f) {
    _Float16 h = (_Float16)f;
    unsigned short r;
    __builtin_memcpy(&r, &h, 2);
    return r;
}

// ---------- async global->LDS (width 16) ----------
__device__ inline void gload16(const void* g, void* lds) {
    unsigned loff = (unsigned)(uintptr_t)lds;
    loff = __builtin_amdgcn_readfirstlane(loff);
    auto l = (__attribute__((address_space(3))) unsigned int*)(uintptr_t)loff;
    auto p = (const __attribute__((address_space(1))) unsigned int*)(uintptr_t)g;
    __builtin_amdgcn_global_load_lds(p, l, 16, 0, 0);
}

// =====================================================================
// Batched elementwise f32 -> 2-byte: y=0 key->f16, y=1 query->f16, y=2 value->bf16
// =====================================================================
__global__ void cvt3_f32_2b(const float4* __restrict__ k, const float4* __restrict__ q,
                            const float4* __restrict__ v,
                            ushort4_t* __restrict__ k16, ushort4_t* __restrict__ q16,
                            ushort4_t* __restrict__ v16, int n4) {
    const int which = blockIdx.y;
    const float4* in  = which == 0 ? k   : which == 1 ? q   : v;
    ushort4_t*    out = which == 0 ? k16 : which == 1 ? q16 : v16;
    const bool tof16 = (which < 2);
    for (int i = blockIdx.x * blockDim.x + threadIdx.x; i < n4; i += gridDim.x * blockDim.x) {
        float4 vv = in[i];
        ushort4_t r;
        if (tof16) { r.x = f2h(vv.x);  r.y = f2h(vv.y);  r.z = f2h(vv.z);  r.w = f2h(vv.w); }
        else       { r.x = f2bf(vv.x); r.y = f2bf(vv.y); r.z = f2bf(vv.z); r.w = f2bf(vv.w); }
        out[i] = r;
    }
}

// =====================================================================
// Weight transpose + convert: W[dim][dim] f32 -> WT[n][k] 2-byte
// =====================================================================
template<int TOF16>
__global__ void transpose_cvt(const float* __restrict__ W, unsigned short* __restrict__ WT, int dim) {
    __shared__ float t[32][33];
    const int bx = blockIdx.x * 32, by = blockIdx.y * 32;   // bx: n, by: k
    const int tx = threadIdx.x, ty = threadIdx.y;
#pragma unroll
    for (int i = 0; i < 4; ++i)
        t[ty + 8 * i][tx] = W[(size_t)(by + ty + 8 * i) * dim + bx + tx];
    __syncthreads();
#pragma unroll
    for (int i = 0; i < 4; ++i) {
        float v = t[tx][ty + 8 * i];
        WT[(size_t)(bx + ty + 8 * i) * dim + by + tx] = TOF16 ? f2h(v) : f2bf(v);
    }
}

// =====================================================================
// v [128][1024][64] bf16 -> vT [128][64][1024] bf16
// =====================================================================
__global__ void transpose_v(const unsigned short* __restrict__ v, unsigned short* __restrict__ vT) {
    const int bh = blockIdx.z, d0 = blockIdx.x * 32, s0 = blockIdx.y * 32;
    __shared__ unsigned short t[32][33];
    const int tx = threadIdx.x, ty = threadIdx.y;
    const size_t base = (size_t)bh << 16;
#pragma unroll
    for (int i = 0; i < 4; ++i)
        t[ty + 8 * i][tx] = v[base + (size_t)(s0 + ty + 8 * i) * 64 + d0 + tx];
    __syncthreads();
#pragma unroll
    for (int i = 0; i < 4; ++i)
        vT[base + (size_t)(d0 + ty + 8 * i) * 1024 + s0 + tx] = t[tx][ty + 8 * i];
}

// =====================================================================
// GEMM (B^T form), 2-phase double-buffered (T3 minimum):
//   stage(k+1) -> s_waitcnt vmcnt(4) -> raw s_barrier -> MFMA(k) -> s_barrier.
// Counted vmcnt keeps next tile's 4 global_load_lds in flight across the
// compute phase; raw barriers avoid __syncthreads' full vmcnt(0) drain.
// 128x128 tile, BK=32, 4 waves (2x2), LDS 32KB (2 bufs).
// EPI 0: store 2-byte (f16/bf16 per F16IN). EPI 1: f32 store of acc+bias+resid.
// =====================================================================
template<int F16IN, int EPI>
__global__ __launch_bounds__(256, 2) void gemm_bt(
    const unsigned short* __restrict__ A,
    const unsigned short* __restrict__ Bt,
    const float* __restrict__ bias,
    unsigned short* __restrict__ C2b,
    const float* __restrict__ resid,
    float* __restrict__ Cf,
    int M, int N, int K, int nbx)
{
    // XCD-chunked bijective swizzle (gridDim.x % 8 == 0)
    const int bid = blockIdx.x;
    const int cpx = gridDim.x >> 3;
    const int swz = (bid & 7) * cpx + (bid >> 3);
    const int bm = swz / nbx, bn = swz % nbx;
    const int m0 = bm * 128, n0 = bn * 128;

    const int tid = threadIdx.x;
    const int w = tid >> 6, l = tid & 63, g = l >> 4, c = l & 15;
    const int wr = w >> 1, wc = w & 1;

    __shared__ unsigned short As[2][4096];   // 2 x [128][32]
    __shared__ unsigned short Bs[2][4096];

    f32x4 acc[4][4] = {};

    const int arow = tid >> 2, acol = (tid & 3) * 8;
    const unsigned short* Ap  = A  + (size_t)(m0 + arow) * K + acol;
    const unsigned short* Ap2 = A  + (size_t)(m0 + 64 + arow) * K + acol;
    const unsigned short* Bp  = Bt + (size_t)(n0 + arow) * K + acol;
    const unsigned short* Bp2 = Bt + (size_t)(n0 + 64 + arow) * K + acol;

    const int NT = K >> 5;   // 32-wide K-steps

#define STAGE_GEMM(bufi, koff)                                   \
    do {                                                         \
        gload16(Ap  + (koff), &As[bufi][w * 512]);               \
        gload16(Ap2 + (koff), &As[bufi][2048 + w * 512]);        \
        gload16(Bp  + (koff), &Bs[bufi][w * 512]);               \
        gload16(Bp2 + (koff), &Bs[bufi][2048 + w * 512]);        \
    } while (0)

#define COMPUTE_GEMM(bufi)                                                         \
    do {                                                                           \
        if constexpr (F16IN) {                                                     \
            f16x8 a[4], b[4];                                                      \
            _Pragma("unroll")                                                      \
            for (int mt = 0; mt < 4; ++mt)                                         \
                a[mt] = *(const f16x8*)&As[bufi][(wr * 64 + mt * 16 + c) * 32 + g * 8]; \
            _Pragma("unroll")                                                      \
            for (int nt = 0; nt < 4; ++nt)                                         \
                b[nt] = *(const f16x8*)&Bs[bufi][(wc * 64 + nt * 16 + c) * 32 + g * 8]; \
            _Pragma("unroll")                                                      \
            for (int mt = 0; mt < 4; ++mt)                                         \
                _Pragma("unroll")                                                  \
                for (int nt = 0; nt < 4; ++nt)                                     \
                    acc[mt][nt] = __builtin_amdgcn_mfma_f32_16x16x32_f16(a[mt], b[nt], acc[mt][nt], 0, 0, 0); \
        } else {                                                                   \
            short8 a[4], b[4];                                                     \
            _Pragma("unroll")                                                      \
            for (int mt = 0; mt < 4; ++mt)                                         \
                a[mt] = *(const short8*)&As[bufi][(wr * 64 + mt * 16 + c) * 32 + g * 8]; \
            _Pragma("unroll")                                                      \
            for (int nt = 0; nt < 4; ++nt)                                         \
                b[nt] = *(const short8*)&Bs[bufi][(wc * 64 + nt * 16 + c) * 32 + g * 8]; \
            _Pragma("unroll")                                                      \
            for (int mt = 0; mt < 4; ++mt)                                         \
                _Pragma("unroll")                                                  \
                for (int nt = 0; nt < 4; ++nt)                                     \
                    acc[mt][nt] = __builtin_amdgcn_mfma_f32_16x16x32_bf16(a[mt], b[nt], acc[mt][nt], 0, 0, 0); \
        }                                                                          \
    } while (0)

    // prologue: stage tile 0
    STAGE_GEMM(0, 0);

#pragma unroll 2
    for (int kt = 0; kt < NT - 1; ++kt) {
        const int cur = kt & 1;
        STAGE_GEMM(cur ^ 1, (kt + 1) * 32);               // next tile in flight
        asm volatile("s_waitcnt vmcnt(4)" ::: "memory");  // current tile's 4 loads done
        __builtin_amdgcn_s_barrier();                     // raw: no vmcnt(0) drain
        __builtin_amdgcn_sched_barrier(0);
        COMPUTE_GEMM(cur);
        __builtin_amdgcn_sched_barrier(0);
        __builtin_amdgcn_s_barrier();                     // all waves done reading buf[cur]
    }
    // last tile
    asm volatile("s_waitcnt vmcnt(0)" ::: "memory");
    __builtin_amdgcn_s_barrier();
    __builtin_amdgcn_sched_barrier(0);
    COMPUTE_GEMM((NT - 1) & 1);

#undef STAGE_GEMM
#undef COMPUTE_GEMM

    // epilogue
#pragma unroll
    for (int nt = 0; nt < 4; ++nt) {
        const int col = n0 + wc * 64 + nt * 16 + c;
        const float bs = bias[col];
#pragma unroll
        for (int mt = 0; mt < 4; ++mt) {
            const int row0 = m0 + wr * 64 + mt * 16 + g * 4;
#pragma unroll
            for (int r = 0; r < 4; ++r) {
                const float x = acc[mt][nt][r] + bs;
                const size_t idx = (size_t)(row0 + r) * N + col;
                if constexpr (EPI == 0) {
                    C2b[idx] = F16IN ? f2h(x) : f2bf(x);
                } else {
                    Cf[idx] = x + resid[idx];
                }
            }
        }
    }
}

// =====================================================================
// Attention v6 (unchanged from round 7, best known):
//  swapped QK^T; packed bf16 pks[16]; PV loop with interleaved NT stores;
//  XCD-chunked decode. One block = (bh, 16 q-rows); 4 waves x 256 k-cols.
// =====================================================================
__global__ __launch_bounds__(256, 4) void attn_kernel(
    const unsigned short* __restrict__ qf,   // f16  [128*1024*64]
    const unsigned short* __restrict__ kf,   // f16  [128*1024*64]
    const unsigned short* __restrict__ vT,   // bf16 [128][64][1024]
    float* __restrict__ attn_out,            // f32  [128][1024][1024]
    unsigned short* __restrict__ ctx)        // bf16 [128*1024*64]
{
    const int L = blockIdx.x;
    const int rb = (L >> 3) & 63;
    const int bh = ((L & 7) << 4) | (L >> 9);

    const int tid = threadIdx.x;
    const int w = tid >> 6, l = tid & 63, g = l >> 4, c = l & 15;
    const int n0 = w * 256;

    __shared__ unsigned short P[16 * 1024];  // 32 KB, XOR-swizzled by (row&7)<<4
    __shared__ float rs_lds[4][16];
    __shared__ float inv_lds[16];

    // Q fragment (B-operand): lane holds Q[row = rb*16 + c][d = g*8 .. +7] (+32)
    const unsigned short* qb = qf + ((size_t)bh << 16) + (size_t)(rb * 16 + c) * 64 + g * 8;
    const f16x8 q0 = *(const f16x8*)(qb);
    const f16x8 q1 = *(const f16x8*)(qb + 32);

    const unsigned short* kb = kf + ((size_t)bh << 16);
    const unsigned swzc = ((unsigned)(c & 7)) << 4;
    const unsigned prow = (unsigned)c * 2048;

    ushort4_t pks[16];
    float rsum = 0.f;

#pragma unroll
    for (int t = 0; t < 16; ++t) {
        const unsigned short* kp = kb + (size_t)(n0 + t * 16 + c) * 64 + g * 8;
        const f16x8 a0 = *(const f16x8*)(kp);
        const f16x8 a1 = *(const f16x8*)(kp + 32);
        f32x4 s = {0.f, 0.f, 0.f, 0.f};
        s = __builtin_amdgcn_mfma_f32_16x16x32_f16(a0, q0, s, 0, 0, 0);
        s = __builtin_amdgcn_mfma_f32_16x16x32_f16(a1, q1, s, 0, 0, 0);

        const float p0 = __expf(s[0] * 0.5f);
        const float p1 = __expf(s[1] * 0.5f);
        const float p2 = __expf(s[2] * 0.5f);
        const float p3 = __expf(s[3] * 0.5f);
        rsum += (p0 + p1) + (p2 + p3);

        ushort4_t pk;
        pk.x = f2bf(p0); pk.y = f2bf(p1); pk.z = f2bf(p2); pk.w = f2bf(p3);
        pks[t] = pk;
        *(ushort4_t*)((char*)P + ((prow + (unsigned)(n0 * 2 + t * 32 + g * 8)) ^ swzc)) = pk;
    }

    rsum += __shfl_xor(rsum, 16);
    rsum += __shfl_xor(rsum, 32);
    if (g == 0) rs_lds[w][c] = rsum;
    __syncthreads();
    if (tid < 16)
        inv_lds[tid] = 1.0f / (rs_lds[0][tid] + rs_lds[1][tid] + rs_lds[2][tid] + rs_lds[3][tid]);
    __syncthreads();

    const float inv = inv_lds[c];
    float* ao = attn_out + ((size_t)bh << 20) + (size_t)(rb * 16 + c) * 1024 + n0 + g * 4;
    f32x4 pacc = {0.f, 0.f, 0.f, 0.f};
    const unsigned short* vb = vT + ((size_t)bh << 16) + (size_t)(w * 16 + c) * 1024;
#pragma unroll
    for (int ks = 0; ks < 32; ++ks) {
        const short8 a = *(const short8*)((char*)P + ((prow + (unsigned)(ks * 64 + g * 16)) ^ swzc));
        const short8 b = *(const short8*)(vb + ks * 32 + g * 8);
        pacc = __builtin_amdgcn_mfma_f32_16x16x32_bf16(a, b, pacc, 0, 0, 0);
        if (ks & 1) {
            const int t = ks >> 1;
            const ushort4_t pk = pks[t];
            f32x4 o;
            o[0] = bf2f(pk.x) * inv;
            o[1] = bf2f(pk.y) * inv;
            o[2] = bf2f(pk.z) * inv;
            o[3] = bf2f(pk.w) * inv;
            __builtin_nontemporal_store(o, (f32x4*)(ao + t * 16));
        }
    }
    unsigned short* cb = ctx + ((size_t)bh << 16) + (size_t)(rb * 16) * 64 + w * 16 + c;
#pragma unroll
    for (int r = 0; r < 4; ++r) {
        const int row = g * 4 + r;
        cb[(size_t)row * 64] = f2bf(pacc[r] * inv_lds[row]);
    }
}

// =====================================================================
// BatchNorm over channels (deterministic two-level reduction)
// =====================================================================
__global__ void bn_stats(const float* __restrict__ x, float* __restrict__ psum, float* __restrict__ psq) {
    const int col = blockIdx.y * 256 + threadIdx.x;   // grid.y = 4
    const int r0 = blockIdx.x * 128;                  // grid.x = 64
    float s = 0.f, q = 0.f;
#pragma unroll 4
    for (int r = 0; r < 128; ++r) {
        const float v = x[(size_t)(r0 + r) * 1024 + col];
        s += v; q += v * v;
    }
    psum[blockIdx.x * 1024 + col] = s;
    psq [blockIdx.x * 1024 + col] = q;
}

__global__ void bn_final(const float* __restrict__ psum, const float* __restrict__ psq,
                         const float* __restrict__ gamma, const float* __restrict__ beta,
                         float* __restrict__ ab) {
    const int cidx = threadIdx.x;   // 1024 threads
    float s = 0.f, q = 0.f;
#pragma unroll 8
    for (int i = 0; i < 64; ++i) { s += psum[i * 1024 + cidx]; q += psq[i * 1024 + cidx]; }
    const float mean = s * (1.0f / 8192.0f);
    const float var  = q * (1.0f / 8192.0f) - mean * mean;
    const float a = gamma[cidx] * rsqrtf(var + 1e-5f);
    ab[cidx]        = a;
    ab[1024 + cidx] = beta[cidx] - mean * a;
}

__global__ void bn_apply(const float4* __restrict__ x4, const float* __restrict__ ab, float4* __restrict__ o4) {
    const int n4 = 2 * 1024 * 1024;
    for (int i = blockIdx.x * blockDim.x + threadIdx.x; i < n4; i += gridDim.x * blockDim.x) {
        const float4 v = x4[i];
        const int c0 = (i & 255) << 2;
        float4 r;
        r.x = v.x * ab[c0 + 0] + ab[1024 + c0 + 0];
        r.y = v.y * ab[c0 + 1] + ab[1024 + c0 + 1];
        r.z = v.z * ab[c0 + 2] + ab[1024 + c0 + 2];
        r.w = v.w * ab[c0 + 3] + ab[1024 + c0 + 3];
        o4[i] = r;
    }
}

// =====================================================================
// launch
// =====================================================================
extern "C" void kernel_launch(void* const* d_in, const int* in_sizes, int n_in,
                              void* d_out, int out_size, void* d_ws, size_t ws_size,
                              hipStream_t stream) {
    (void)in_sizes; (void)n_in; (void)out_size; (void)ws_size;

    const float* key   = (const float*)d_in[0];
    const float* value = (const float*)d_in[1];
    const float* query = (const float*)d_in[2];
    const float* Wk = (const float*)d_in[3];
    const float* bk = (const float*)d_in[4];
    const float* Wv = (const float*)d_in[5];
    const float* bv = (const float*)d_in[6];
    const float* Wq = (const float*)d_in[7];
    const float* bq = (const float*)d_in[8];
    const float* Wf = (const float*)d_in[9];
    const float* bff = (const float*)d_in[10];
    const float* gamma = (const float*)d_in[11];
    const float* beta  = (const float*)d_in[12];

    char* ws = (char*)d_ws;
    const size_t MB = 1u << 20;
    // layout (with safe overlap reuse):
    unsigned short* key16   = (unsigned short*)(ws + 0);        // dead after GEMM-k -> reused as ctx
    unsigned short* ctx     = (unsigned short*)(ws + 0);
    unsigned short* query16 = (unsigned short*)(ws + 16 * MB);  // dead after GEMM-q -+
    unsigned short* value16 = (unsigned short*)(ws + 32 * MB);  // dead after GEMM-v -+-> reused as xbuf
    float*          xbuf    = (float*)(ws + 16 * MB);           // 32 MB
    unsigned short* WkT = (unsigned short*)(ws + 48 * MB);
    unsigned short* WqT = (unsigned short*)(ws + 50 * MB);
    unsigned short* WvT = (unsigned short*)(ws + 52 * MB);
    unsigned short* WfT = (unsigned short*)(ws + 54 * MB);
    unsigned short* kbuf = (unsigned short*)(ws + 56 * MB);
    unsigned short* qbuf = (unsigned short*)(ws + 72 * MB);
    unsigned short* vbuf = (unsigned short*)(ws + 88 * MB);     // dead after transpose_v -> stats
    float* psum = (float*)(ws + 88 * MB);
    float* psq  = (float*)(ws + 88 * MB + 256 * 1024);
    float* ab   = (float*)(ws + 88 * MB + 512 * 1024);
    unsigned short* vTbuf = (unsigned short*)(ws + 104 * MB);
    // total: 120 MB

    float* out0 = (float*)d_out;            // [8M]  normalized output
    float* attn = out0 + 8388608;           // [128M] attention

    const int n4big = 2 * 1024 * 1024;      // 8M floats / 4

    // 1) input conversions (single batched launch)
    cvt3_f32_2b<<<dim3(1024, 3), 256, 0, stream>>>(
        (const float4*)key, (const float4*)query, (const float4*)value,
        (ushort4_t*)key16, (ushort4_t*)query16, (ushort4_t*)value16, n4big);

    // 2) weight transposes
    dim3 tb(32, 8), tg(32, 32);
    transpose_cvt<1><<<tg, tb, 0, stream>>>(Wk, WkT, 1024);
    transpose_cvt<1><<<tg, tb, 0, stream>>>(Wq, WqT, 1024);
    transpose_cvt<0><<<tg, tb, 0, stream>>>(Wv, WvT, 1024);
    transpose_cvt<0><<<tg, tb, 0, stream>>>(Wf, WfT, 1024);

    // 3) QKV projections (M=8192, N=1024, K=1024), f16 for q/k, bf16 for v
    gemm_bt<1, 0><<<512, 256, 0, stream>>>(key16,   WkT, bk, kbuf, nullptr, nullptr, 8192, 1024, 1024, 8);
    gemm_bt<1, 0><<<512, 256, 0, stream>>>(query16, WqT, bq, qbuf, nullptr, nullptr, 8192, 1024, 1024, 8);
    gemm_bt<0, 0><<<512, 256, 0, stream>>>(value16, WvT, bv, vbuf, nullptr, nullptr, 8192, 1024, 1024, 8);

    // 4) v -> vT per head-batch
    transpose_v<<<dim3(2, 32, 128), tb, 0, stream>>>(vbuf, vTbuf);

    // 5) attention (writes attention matrix + ctx), XCD-chunked 1-D grid
    attn_kernel<<<8192, 256, 0, stream>>>(qbuf, kbuf, vTbuf, attn, ctx);

    // 6) output projection + residual -> xbuf (f32)
    gemm_bt<0, 1><<<512, 256, 0, stream>>>(ctx, WfT, bff, nullptr, query, xbuf, 8192, 1024, 1024, 8);

    // 7) BatchNorm (deterministic)
    bn_stats<<<dim3(64, 4), 256, 0, stream>>>(xbuf, psum, psq);
    bn_final<<<1, 1024, 0, stream>>>(psum, psq, gamma, beta, ab);
    bn_apply<<<2048, 256, 0, stream>>>((const float4*)xbuf, ab, (float4*)out0);
}

// Round 9
// 443.594 us; speedup vs baseline: 1.2682x; 1.0089x over previous
//
#include <hip/hip_runtime.h>
#include <hip/hip_bf16.h>
#include <stdint.h>

// ---------- types ----------
typedef __attribute__((ext_vector_type(8))) short     short8;   // 8 bf16 (raw bits)
typedef __attribute__((ext_vector_type(8))) _Float16  f16x8;    // 8 fp16
typedef __attribute__((ext_vector_type(4))) float     f32x4;
typedef __attribute__((ext_vector_type(8))) unsigned short ushort8;
typedef __attribute__((ext_vector_type(4))) unsigned short ushort4_t;

// ---------- scalar conversion helpers ----------
__device__ inline unsigned short f2bf(float f) {
    unsigned u = __float_as_uint(f);
    u += 0x7fffu + ((u >> 16) & 1u);          // RNE
    return (unsigned short)(u >> 16);
}
__device__ inline float bf2f(unsigned short h) {
    return __uint_as_float(((unsigned)h) << 16);
}
__device__ inline unsigned short f2h(float f) {
    _Float16 h = (_Float16)f;
    unsigned short r;
    __builtin_memcpy(&r, &h, 2);
    return r;
}

// ---------- async global->LDS (width 16) ----------
__device__ inline void gload16(const void* g, void* lds) {
    unsigned loff = (unsigned)(uintptr_t)lds;
    loff = __builtin_amdgcn_readfirstlane(loff);
    auto l = (__attribute__((address_space(3))) unsigned int*)(uintptr_t)loff;
    auto p = (const __attribute__((address_space(1))) unsigned int*)(uintptr_t)g;
    __builtin_amdgcn_global_load_lds(p, l, 16, 0, 0);
}

// =====================================================================
// Batched elementwise f32 -> 2-byte: y=0 key->f16, y=1 query->f16, y=2 value->bf16
// =====================================================================
__global__ void cvt3_f32_2b(const float4* __restrict__ k, const float4* __restrict__ q,
                            const float4* __restrict__ v,
                            ushort4_t* __restrict__ k16, ushort4_t* __restrict__ q16,
                            ushort4_t* __restrict__ v16, int n4) {
    const int which = blockIdx.y;
    const float4* in  = which == 0 ? k   : which == 1 ? q   : v;
    ushort4_t*    out = which == 0 ? k16 : which == 1 ? q16 : v16;
    const bool tof16 = (which < 2);
    for (int i = blockIdx.x * blockDim.x + threadIdx.x; i < n4; i += gridDim.x * blockDim.x) {
        float4 vv = in[i];
        ushort4_t r;
        if (tof16) { r.x = f2h(vv.x);  r.y = f2h(vv.y);  r.z = f2h(vv.z);  r.w = f2h(vv.w); }
        else       { r.x = f2bf(vv.x); r.y = f2bf(vv.y); r.z = f2bf(vv.z); r.w = f2bf(vv.w); }
        out[i] = r;
    }
}

// =====================================================================
// Weight transpose + convert: W[dim][dim] f32 -> WT[n][k] 2-byte
// =====================================================================
template<int TOF16>
__global__ void transpose_cvt(const float* __restrict__ W, unsigned short* __restrict__ WT, int dim) {
    __shared__ float t[32][33];
    const int bx = blockIdx.x * 32, by = blockIdx.y * 32;   // bx: n, by: k
    const int tx = threadIdx.x, ty = threadIdx.y;
#pragma unroll
    for (int i = 0; i < 4; ++i)
        t[ty + 8 * i][tx] = W[(size_t)(by + ty + 8 * i) * dim + bx + tx];
    __syncthreads();
#pragma unroll
    for (int i = 0; i < 4; ++i) {
        float v = t[tx][ty + 8 * i];
        WT[(size_t)(bx + ty + 8 * i) * dim + by + tx] = TOF16 ? f2h(v) : f2bf(v);
    }
}

// =====================================================================
// v [128][1024][64] bf16 -> vT [128][64][1024] bf16
// =====================================================================
__global__ void transpose_v(const unsigned short* __restrict__ v, unsigned short* __restrict__ vT) {
    const int bh = blockIdx.z, d0 = blockIdx.x * 32, s0 = blockIdx.y * 32;
    __shared__ unsigned short t[32][33];
    const int tx = threadIdx.x, ty = threadIdx.y;
    const size_t base = (size_t)bh << 16;
#pragma unroll
    for (int i = 0; i < 4; ++i)
        t[ty + 8 * i][tx] = v[base + (size_t)(s0 + ty + 8 * i) * 64 + d0 + tx];
    __syncthreads();
#pragma unroll
    for (int i = 0; i < 4; ++i)
        vT[base + (size_t)(d0 + ty + 8 * i) * 1024 + s0 + tx] = t[tx][ty + 8 * i];
}

// =====================================================================
// GEMM (B^T form), 2-phase double-buffered (T3 minimum):
//   stage(k+1) -> s_waitcnt vmcnt(4) -> raw s_barrier -> MFMA(k) -> s_barrier.
// Counted vmcnt keeps next tile's 4 global_load_lds in flight across the
// compute phase; raw barriers avoid __syncthreads' full vmcnt(0) drain.
// 128x128 tile, BK=32, 4 waves (2x2), LDS 32KB (2 bufs).
// EPI 0: store 2-byte (f16/bf16 per F16IN). EPI 1: f32 store of acc+bias+resid.
// =====================================================================
template<int F16IN, int EPI>
__global__ __launch_bounds__(256, 2) void gemm_bt(
    const unsigned short* __restrict__ A,
    const unsigned short* __restrict__ Bt,
    const float* __restrict__ bias,
    unsigned short* __restrict__ C2b,
    const float* __restrict__ resid,
    float* __restrict__ Cf,
    int M, int N, int K, int nbx)
{
    // XCD-chunked bijective swizzle (gridDim.x % 8 == 0)
    const int bid = blockIdx.x;
    const int cpx = gridDim.x >> 3;
    const int swz = (bid & 7) * cpx + (bid >> 3);
    const int bm = swz / nbx, bn = swz % nbx;
    const int m0 = bm * 128, n0 = bn * 128;

    const int tid = threadIdx.x;
    const int w = tid >> 6, l = tid & 63, g = l >> 4, c = l & 15;
    const int wr = w >> 1, wc = w & 1;

    __shared__ unsigned short As[2][4096];   // 2 x [128][32]
    __shared__ unsigned short Bs[2][4096];

    f32x4 acc[4][4] = {};

    const int arow = tid >> 2, acol = (tid & 3) * 8;
    const unsigned short* Ap  = A  + (size_t)(m0 + arow) * K + acol;
    const unsigned short* Ap2 = A  + (size_t)(m0 + 64 + arow) * K + acol;
    const unsigned short* Bp  = Bt + (size_t)(n0 + arow) * K + acol;
    const unsigned short* Bp2 = Bt + (size_t)(n0 + 64 + arow) * K + acol;

    const int NT = K >> 5;   // 32-wide K-steps

#define STAGE_GEMM(bufi, koff)                                   \
    do {                                                         \
        gload16(Ap  + (koff), &As[bufi][w * 512]);               \
        gload16(Ap2 + (koff), &As[bufi][2048 + w * 512]);        \
        gload16(Bp  + (koff), &Bs[bufi][w * 512]);               \
        gload16(Bp2 + (koff), &Bs[bufi][2048 + w * 512]);        \
    } while (0)

#define COMPUTE_GEMM(bufi)                                                         \
    do {                                                                           \
        if constexpr (F16IN) {                                                     \
            f16x8 a[4], b[4];                                                      \
            _Pragma("unroll")                                                      \
            for (int mt = 0; mt < 4; ++mt)                                         \
                a[mt] = *(const f16x8*)&As[bufi][(wr * 64 + mt * 16 + c) * 32 + g * 8]; \
            _Pragma("unroll")                                                      \
            for (int nt = 0; nt < 4; ++nt)                                         \
                b[nt] = *(const f16x8*)&Bs[bufi][(wc * 64 + nt * 16 + c) * 32 + g * 8]; \
            _Pragma("unroll")                                                      \
            for (int mt = 0; mt < 4; ++mt)                                         \
                _Pragma("unroll")                                                  \
                for (int nt = 0; nt < 4; ++nt)                                     \
                    acc[mt][nt] = __builtin_amdgcn_mfma_f32_16x16x32_f16(a[mt], b[nt], acc[mt][nt], 0, 0, 0); \
        } else {                                                                   \
            short8 a[4], b[4];                                                     \
            _Pragma("unroll")                                                      \
            for (int mt = 0; mt < 4; ++mt)                                         \
                a[mt] = *(const short8*)&As[bufi][(wr * 64 + mt * 16 + c) * 32 + g * 8]; \
            _Pragma("unroll")                                                      \
            for (int nt = 0; nt < 4; ++nt)                                         \
                b[nt] = *(const short8*)&Bs[bufi][(wc * 64 + nt * 16 + c) * 32 + g * 8]; \
            _Pragma("unroll")                                                      \
            for (int mt = 0; mt < 4; ++mt)                                         \
                _Pragma("unroll")                                                  \
                for (int nt = 0; nt < 4; ++nt)                                     \
                    acc[mt][nt] = __builtin_amdgcn_mfma_f32_16x16x32_bf16(a[mt], b[nt], acc[mt][nt], 0, 0, 0); \
        }                                                                          \
    } while (0)

    // prologue: stage tile 0
    STAGE_GEMM(0, 0);

#pragma unroll 2
    for (int kt = 0; kt < NT - 1; ++kt) {
        const int cur = kt & 1;
        STAGE_GEMM(cur ^ 1, (kt + 1) * 32);               // next tile in flight
        asm volatile("s_waitcnt vmcnt(4)" ::: "memory");  // current tile's 4 loads done
        __builtin_amdgcn_s_barrier();                     // raw: no vmcnt(0) drain
        __builtin_amdgcn_sched_barrier(0);
        COMPUTE_GEMM(cur);
        __builtin_amdgcn_sched_barrier(0);
        __builtin_amdgcn_s_barrier();                     // all waves done reading buf[cur]
    }
    // last tile
    asm volatile("s_waitcnt vmcnt(0)" ::: "memory");
    __builtin_amdgcn_s_barrier();
    __builtin_amdgcn_sched_barrier(0);
    COMPUTE_GEMM((NT - 1) & 1);

#undef STAGE_GEMM
#undef COMPUTE_GEMM

    // epilogue
#pragma unroll
    for (int nt = 0; nt < 4; ++nt) {
        const int col = n0 + wc * 64 + nt * 16 + c;
        const float bs = bias[col];
#pragma unroll
        for (int mt = 0; mt < 4; ++mt) {
            const int row0 = m0 + wr * 64 + mt * 16 + g * 4;
#pragma unroll
            for (int r = 0; r < 4; ++r) {
                const float x = acc[mt][nt][r] + bs;
                const size_t idx = (size_t)(row0 + r) * N + col;
                if constexpr (EPI == 0) {
                    C2b[idx] = F16IN ? f2h(x) : f2bf(x);
                } else {
                    Cf[idx] = x + resid[idx];
                }
            }
        }
    }
}

// =====================================================================
// Attention v6 (unchanged from round 7, best known):
//  swapped QK^T; packed bf16 pks[16]; PV loop with interleaved NT stores;
//  XCD-chunked decode. One block = (bh, 16 q-rows); 4 waves x 256 k-cols.
// =====================================================================
__global__ __launch_bounds__(256, 4) void attn_kernel(
    const unsigned short* __restrict__ qf,   // f16  [128*1024*64]
    const unsigned short* __restrict__ kf,   // f16  [128*1024*64]
    const unsigned short* __restrict__ vT,   // bf16 [128][64][1024]
    float* __restrict__ attn_out,            // f32  [128][1024][1024]
    unsigned short* __restrict__ ctx)        // bf16 [128*1024*64]
{
    const int L = blockIdx.x;
    const int rb = (L >> 3) & 63;
    const int bh = ((L & 7) << 4) | (L >> 9);

    const int tid = threadIdx.x;
    const int w = tid >> 6, l = tid & 63, g = l >> 4, c = l & 15;
    const int n0 = w * 256;

    __shared__ unsigned short P[16 * 1024];  // 32 KB, XOR-swizzled by (row&7)<<4
    __shared__ float rs_lds[4][16];
    __shared__ float inv_lds[16];

    // Q fragment (B-operand): lane holds Q[row = rb*16 + c][d = g*8 .. +7] (+32)
    const unsigned short* qb = qf + ((size_t)bh << 16) + (size_t)(rb * 16 + c) * 64 + g * 8;
    const f16x8 q0 = *(const f16x8*)(qb);
    const f16x8 q1 = *(const f16x8*)(qb + 32);

    const unsigned short* kb = kf + ((size_t)bh << 16);
    const unsigned swzc = ((unsigned)(c & 7)) << 4;
    const unsigned prow = (unsigned)c * 2048;

    ushort4_t pks[16];
    float rsum = 0.f;

#pragma unroll
    for (int t = 0; t < 16; ++t) {
        const unsigned short* kp = kb + (size_t)(n0 + t * 16 + c) * 64 + g * 8;
        const f16x8 a0 = *(const f16x8*)(kp);
        const f16x8 a1 = *(const f16x8*)(kp + 32);
        f32x4 s = {0.f, 0.f, 0.f, 0.f};
        s = __builtin_amdgcn_mfma_f32_16x16x32_f16(a0, q0, s, 0, 0, 0);
        s = __builtin_amdgcn_mfma_f32_16x16x32_f16(a1, q1, s, 0, 0, 0);

        const float p0 = __expf(s[0] * 0.5f);
        const float p1 = __expf(s[1] * 0.5f);
        const float p2 = __expf(s[2] * 0.5f);
        const float p3 = __expf(s[3] * 0.5f);
        rsum += (p0 + p1) + (p2 + p3);

        ushort4_t pk;
        pk.x = f2bf(p0); pk.y = f2bf(p1); pk.z = f2bf(p2); pk.w = f2bf(p3);
        pks[t] = pk;
        *(ushort4_t*)((char*)P + ((prow + (unsigned)(n0 * 2 + t * 32 + g * 8)) ^ swzc)) = pk;
    }

    rsum += __shfl_xor(rsum, 16);
    rsum += __shfl_xor(rsum, 32);
    if (g == 0) rs_lds[w][c] = rsum;
    __syncthreads();
    if (tid < 16)
        inv_lds[tid] = 1.0f / (rs_lds[0][tid] + rs_lds[1][tid] + rs_lds[2][tid] + rs_lds[3][tid]);
    __syncthreads();

    const float inv = inv_lds[c];
    float* ao = attn_out + ((size_t)bh << 20) + (size_t)(rb * 16 + c) * 1024 + n0 + g * 4;
    f32x4 pacc = {0.f, 0.f, 0.f, 0.f};
    const unsigned short* vb = vT + ((size_t)bh << 16) + (size_t)(w * 16 + c) * 1024;
#pragma unroll
    for (int ks = 0; ks < 32; ++ks) {
        const short8 a = *(const short8*)((char*)P + ((prow + (unsigned)(ks * 64 + g * 16)) ^ swzc));
        const short8 b = *(const short8*)(vb + ks * 32 + g * 8);
        pacc = __builtin_amdgcn_mfma_f32_16x16x32_bf16(a, b, pacc, 0, 0, 0);
        if (ks & 1) {
            const int t = ks >> 1;
            const ushort4_t pk = pks[t];
            f32x4 o;
            o[0] = bf2f(pk.x) * inv;
            o[1] = bf2f(pk.y) * inv;
            o[2] = bf2f(pk.z) * inv;
            o[3] = bf2f(pk.w) * inv;
            __builtin_nontemporal_store(o, (f32x4*)(ao + t * 16));
        }
    }
    unsigned short* cb = ctx + ((size_t)bh << 16) + (size_t)(rb * 16) * 64 + w * 16 + c;
#pragma unroll
    for (int r = 0; r < 4; ++r) {
        const int row = g * 4 + r;
        cb[(size_t)row * 64] = f2bf(pacc[r] * inv_lds[row]);
    }
}

// =====================================================================
// BatchNorm over channels (deterministic two-level reduction)
// =====================================================================
__global__ void bn_stats(const float* __restrict__ x, float* __restrict__ psum, float* __restrict__ psq) {
    const int col = blockIdx.y * 256 + threadIdx.x;   // grid.y = 4
    const int r0 = blockIdx.x * 128;                  // grid.x = 64
    float s = 0.f, q = 0.f;
#pragma unroll 4
    for (int r = 0; r < 128; ++r) {
        const float v = x[(size_t)(r0 + r) * 1024 + col];
        s += v; q += v * v;
    }
    psum[blockIdx.x * 1024 + col] = s;
    psq [blockIdx.x * 1024 + col] = q;
}

__global__ void bn_final(const float* __restrict__ psum, const float* __restrict__ psq,
                         const float* __restrict__ gamma, const float* __restrict__ beta,
                         float* __restrict__ ab) {
    const int cidx = threadIdx.x;   // 1024 threads
    float s = 0.f, q = 0.f;
#pragma unroll 8
    for (int i = 0; i < 64; ++i) { s += psum[i * 1024 + cidx]; q += psq[i * 1024 + cidx]; }
    const float mean = s * (1.0f / 8192.0f);
    const float var  = q * (1.0f / 8192.0f) - mean * mean;
    const float a = gamma[cidx] * rsqrtf(var + 1e-5f);
    ab[cidx]        = a;
    ab[1024 + cidx] = beta[cidx] - mean * a;
}

__global__ void bn_apply(const float4* __restrict__ x4, const float* __restrict__ ab, float4* __restrict__ o4) {
    const int n4 = 2 * 1024 * 1024;
    for (int i = blockIdx.x * blockDim.x + threadIdx.x; i < n4; i += gridDim.x * blockDim.x) {
        const float4 v = x4[i];
        const int c0 = (i & 255) << 2;
        float4 r;
        r.x = v.x * ab[c0 + 0] + ab[1024 + c0 + 0];
        r.y = v.y * ab[c0 + 1] + ab[1024 + c0 + 1];
        r.z = v.z * ab[c0 + 2] + ab[1024 + c0 + 2];
        r.w = v.w * ab[c0 + 3] + ab[1024 + c0 + 3];
        o4[i] = r;
    }
}

// =====================================================================
// launch
// =====================================================================
extern "C" void kernel_launch(void* const* d_in, const int* in_sizes, int n_in,
                              void* d_out, int out_size, void* d_ws, size_t ws_size,
                              hipStream_t stream) {
    (void)in_sizes; (void)n_in; (void)out_size; (void)ws_size;

    const float* key   = (const float*)d_in[0];
    const float* value = (const float*)d_in[1];
    const float* query = (const float*)d_in[2];
    const float* Wk = (const float*)d_in[3];
    const float* bk = (const float*)d_in[4];
    const float* Wv = (const float*)d_in[5];
    const float* bv = (const float*)d_in[6];
    const float* Wq = (const float*)d_in[7];
    const float* bq = (const float*)d_in[8];
    const float* Wf = (const float*)d_in[9];
    const float* bff = (const float*)d_in[10];
    const float* gamma = (const float*)d_in[11];
    const float* beta  = (const float*)d_in[12];

    char* ws = (char*)d_ws;
    const size_t MB = 1u << 20;
    // layout (with safe overlap reuse):
    unsigned short* key16   = (unsigned short*)(ws + 0);        // dead after GEMM-k -> reused as ctx
    unsigned short* ctx     = (unsigned short*)(ws + 0);
    unsigned short* query16 = (unsigned short*)(ws + 16 * MB);  // dead after GEMM-q -+
    unsigned short* value16 = (unsigned short*)(ws + 32 * MB);  // dead after GEMM-v -+-> reused as xbuf
    float*          xbuf    = (float*)(ws + 16 * MB);           // 32 MB
    unsigned short* WkT = (unsigned short*)(ws + 48 * MB);
    unsigned short* WqT = (unsigned short*)(ws + 50 * MB);
    unsigned short* WvT = (unsigned short*)(ws + 52 * MB);
    unsigned short* WfT = (unsigned short*)(ws + 54 * MB);
    unsigned short* kbuf = (unsigned short*)(ws + 56 * MB);
    unsigned short* qbuf = (unsigned short*)(ws + 72 * MB);
    unsigned short* vbuf = (unsigned short*)(ws + 88 * MB);     // dead after transpose_v -> stats
    float* psum = (float*)(ws + 88 * MB);
    float* psq  = (float*)(ws + 88 * MB + 256 * 1024);
    float* ab   = (float*)(ws + 88 * MB + 512 * 1024);
    unsigned short* vTbuf = (unsigned short*)(ws + 104 * MB);
    // total: 120 MB

    float* out0 = (float*)d_out;            // [8M]  normalized output
    float* attn = out0 + 8388608;           // [128M] attention

    const int n4big = 2 * 1024 * 1024;      // 8M floats / 4

    // 1) input conversions (single batched launch)
    cvt3_f32_2b<<<dim3(1024, 3), 256, 0, stream>>>(
        (const float4*)key, (const float4*)query, (const float4*)value,
        (ushort4_t*)key16, (ushort4_t*)query16, (ushort4_t*)value16, n4big);

    // 2) weight transposes
    dim3 tb(32, 8), tg(32, 32);
    transpose_cvt<1><<<tg, tb, 0, stream>>>(Wk, WkT, 1024);
    transpose_cvt<1><<<tg, tb, 0, stream>>>(Wq, WqT, 1024);
    transpose_cvt<0><<<tg, tb, 0, stream>>>(Wv, WvT, 1024);
    transpose_cvt<0><<<tg, tb, 0, stream>>>(Wf, WfT, 1024);

    // 3) QKV projections (M=8192, N=1024, K=1024), f16 for q/k, bf16 for v
    gemm_bt<1, 0><<<512, 256, 0, stream>>>(key16,   WkT, bk, kbuf, nullptr, nullptr, 8192, 1024, 1024, 8);
    gemm_bt<1, 0><<<512, 256, 0, stream>>>(query16, WqT, bq, qbuf, nullptr, nullptr, 8192, 1024, 1024, 8);
    gemm_bt<0, 0><<<512, 256, 0, stream>>>(value16, WvT, bv, vbuf, nullptr, nullptr, 8192, 1024, 1024, 8);

    // 4) v -> vT per head-batch
    transpose_v<<<dim3(2, 32, 128), tb, 0, stream>>>(vbuf, vTbuf);

    // 5) attention (writes attention matrix + ctx), XCD-chunked 1-D grid
    attn_kernel<<<8192, 256, 0, stream>>>(qbuf, kbuf, vTbuf, attn, ctx);

    // 6) output projection + residual -> xbuf (f32)
    gemm_bt<0, 1><<<512, 256, 0, stream>>>(ctx, WfT, bff, nullptr, query, xbuf, 8192, 1024, 1024, 8);

    // 7) BatchNorm (deterministic)
    bn_stats<<<dim3(64, 4), 256, 0, stream>>>(xbuf, psum, psq);
    bn_final<<<1, 1024, 0, stream>>>(psum, psq, gamma, beta, ab);
    bn_apply<<<2048, 256, 0, stream>>>((const float4*)xbuf, ab, (float4*)out0);
}